// Round 13
// baseline (2838.608 us; speedup 1.0000x reference)
//
#include <hip/hip_runtime.h>
#include <hip/hip_bf16.h>
#include <cstdint>
#include <cstddef>

typedef __hip_bfloat16 bf16;
typedef __attribute__((ext_vector_type(8))) short bf16x8;
typedef __attribute__((ext_vector_type(4))) float f32x4;

#define DEV __device__ __forceinline__

static constexpr int D  = 768;
static constexpr int NH = 12;
static constexpr int NE = 4;
static constexpr int DH = 3072;
static constexpr int L  = 1024;
static constexpr int T  = 2048;
static constexpr int V  = 32000;
static constexpr int NL = 4;

static constexpr long PSX = (long)T * 768;        // activation plane stride
static constexpr long PSH = (long)NE * 2048 * DH; // hse plane stride
static constexpr long PSW = (long)NE * DH * 768;  // MoE weight plane stride
static constexpr long PSQ = (long)2304 * 768;     // qkv weight plane stride
static constexpr long PSO = (long)768 * 768;      // o-proj weight plane stride
static constexpr long EB  = (long)DH * 768;       // per-expert weight elems

DEV float b2f(bf16 v) { return __bfloat162float(v); }
DEV bf16 f2b(float f) { return __float2bfloat16(f); }
DEV unsigned short f2bu(float f) {
  bf16 b = f2b(f);
  return *reinterpret_cast<unsigned short*>(&b);
}
DEV float gelu(float v) {
  return 0.5f * v * (1.f + erff(v * 0.70710678118654752f));
}
// Exact fp32 -> 3x bf16 plane decomposition (a ~= p0+p1+p2 to ~2^-24).
DEV void split3u(float a, unsigned short& x0, unsigned short& x1,
                 unsigned short& x2) {
  bf16 c0 = f2b(a);
  float r1 = a - b2f(c0);
  bf16 c1 = f2b(r1);
  float r2 = r1 - b2f(c1);
  bf16 c2 = f2b(r2);
  x0 = *reinterpret_cast<unsigned short*>(&c0);
  x1 = *reinterpret_cast<unsigned short*>(&c1);
  x2 = *reinterpret_cast<unsigned short*>(&c2);
}

// ---------------------------------------------------------------- staging ----
DEV void gld16(const void* g, short* ldsbase, int lane) {
#if __has_builtin(__builtin_amdgcn_global_load_lds)
  (void)lane;
  __builtin_amdgcn_global_load_lds(
      (const __attribute__((address_space(1))) unsigned int*)g,
      (__attribute__((address_space(3))) unsigned int*)ldsbase, 16, 0, 0);
#else
  *reinterpret_cast<bf16x8*>(ldsbase + lane * 8) =
      *reinterpret_cast<const bf16x8*>(g);
#endif
}

// 6-term bf16x3 MFMA accumulate helper (i+j<=2 cross products).
DEV void mfma6(f32x4 acc[4][4], const bf16x8 af[3][4], const short* ldsB,
               int wn, int ln, int kg) {
#pragma unroll
  for (int c = 0; c < 4; ++c) {
    const int bo = (wn + c * 16 + ln) * 32 + kg * 8;
    const bf16x8 bv0 = *reinterpret_cast<const bf16x8*>(&ldsB[bo]);
    const bf16x8 bv1 = *reinterpret_cast<const bf16x8*>(&ldsB[4096 + bo]);
    const bf16x8 bv2 = *reinterpret_cast<const bf16x8*>(&ldsB[8192 + bo]);
#pragma unroll
    for (int r = 0; r < 4; ++r) {
      f32x4 a = acc[r][c];
      a = __builtin_amdgcn_mfma_f32_16x16x32_bf16(af[0][r], bv0, a, 0, 0, 0);
      a = __builtin_amdgcn_mfma_f32_16x16x32_bf16(af[0][r], bv1, a, 0, 0, 0);
      a = __builtin_amdgcn_mfma_f32_16x16x32_bf16(af[1][r], bv0, a, 0, 0, 0);
      a = __builtin_amdgcn_mfma_f32_16x16x32_bf16(af[0][r], bv2, a, 0, 0, 0);
      a = __builtin_amdgcn_mfma_f32_16x16x32_bf16(af[1][r], bv1, a, 0, 0, 0);
      a = __builtin_amdgcn_mfma_f32_16x16x32_bf16(af[2][r], bv0, a, 0, 0, 0);
      acc[r][c] = a;
    }
  }
}

// --------------------------------------- dense bf16x3 fp32-faithful GEMM ----
// C[2048,N] = A @ B + bias; A planes [2048][768], B^T planes [N][768], K=768.
// EPI 1: qkv (elu+1 for col<1536) -> fp32 out. EPI 2: out += acc + bias.
template <int EPI>
__global__ __launch_bounds__(256) void k_g3(
    const bf16* __restrict__ Ap, long psA,
    const bf16* __restrict__ Bp, long psB,
    const float* __restrict__ bias,
    float* __restrict__ outp, int ldc) {
  const int m0 = blockIdx.y * 128;
  const int n0 = blockIdx.x * 128;
  const int tid  = threadIdx.x;
  const int wave = tid >> 6;
  const int lane = tid & 63;
  const int wm = (wave >> 1) * 64;
  const int wn = (wave & 1) * 64;
  const int ln = lane & 15;
  const int kg = lane >> 4;
  const int rowA = lane >> 2;
  const int colK = (lane & 3) * 8;

  __shared__ short lds[24576];  // A planes @0/4096/8192, B planes @12288+

  f32x4 acc[4][4] = {};

  for (int kt = 0; kt < 768; kt += 32) {
    __syncthreads();
#pragma unroll
    for (int c2 = 0; c2 < 2; ++c2) {
      const int chunk = c2 * 4 + wave;
      const int r16 = chunk * 16 + rowA;
      const size_t arow = (size_t)(m0 + r16);
      const size_t brow = (size_t)(n0 + r16);
#pragma unroll
      for (int p = 0; p < 3; ++p) {
        gld16(Ap + (size_t)p * psA + arow * 768 + kt + colK,
              &lds[p * 4096 + chunk * 512], lane);
        gld16(Bp + (size_t)p * psB + brow * 768 + kt + colK,
              &lds[12288 + p * 4096 + chunk * 512], lane);
      }
    }
    __syncthreads();

    bf16x8 af[3][4];
#pragma unroll
    for (int r = 0; r < 4; ++r)
#pragma unroll
      for (int p = 0; p < 3; ++p)
        af[p][r] = *reinterpret_cast<const bf16x8*>(
            &lds[p * 4096 + (wm + r * 16 + ln) * 32 + kg * 8]);
    mfma6(acc, af, &lds[12288], wn, ln, kg);
  }

#pragma unroll
  for (int c = 0; c < 4; ++c) {
    const int col = n0 + wn + c * 16 + ln;
    const float bvl = bias[col];
#pragma unroll
    for (int r = 0; r < 4; ++r)
#pragma unroll
      for (int j = 0; j < 4; ++j) {
        const int row = m0 + wm + r * 16 + kg * 4 + j;
        const float v = acc[r][c][j] + bvl;
        const size_t idx = (size_t)row * ldc + col;
        if constexpr (EPI == 1) {
          outp[idx] = (col < 1536) ? (v > 0.f ? v + 1.f : expf(v)) : v;
        } else {
          outp[idx] += v;
        }
      }
  }
}

// ----------------------------------------- bf16x3 split-precision MoE GEMM --
// PH=0 (UP):  grid (24,16,4). XCD-resident schedule (r13): XCD k owns expert
//             z=k>>1, n-half=k&1; per-XCD order mg(4 groups of 4 by) -> bx(12)
//             -> byi(4). Working set = 4 A-panels (2.36MB) + 1 B-panel
//             (0.59MB) < 4MB L2; traffic ~19MB/XCD (vs 63MB r12).
// PH=1 (DOWN):grid (6,16,16). XCD k owns combos {2k,2k+1} of (z,kc); per-combo
//             order mg(4) -> bx(6) -> byi(4). Split-K 3072=4x768; out
//             xc[(kc*2+rank)][tok][768] fp32.
template <int PH>
__global__ __launch_bounds__(256) void k_moe3(
    const bf16* __restrict__ Ap, long psA,
    const bf16* __restrict__ Bp, long psB,
    const float* __restrict__ b1z,
    bf16* __restrict__ hseP,
    float* __restrict__ xc,
    const float* __restrict__ srow, const int* __restrict__ list,
    const int* __restrict__ rnkl, const int* __restrict__ cnt) {
  int bx, by, z, kc;
  const int bid =
      (blockIdx.z * gridDim.y + blockIdx.y) * gridDim.x + blockIdx.x;
  const int xcd = bid & 7;
  const int idx = bid >> 3;  // [0,192)
  if constexpr (PH == 0) {
    z = xcd >> 1;
    const int half = xcd & 1;
    const int mg = idx / 48;         // [0,4)
    const int rem = idx % 48;
    bx = half * 12 + rem / 4;        // [0,24)
    by = mg * 4 + (rem & 3);         // [0,16)
    kc = 0;
  } else {
    const int combo = xcd * 2 + idx / 96;  // [0,16)
    z = combo >> 2;
    kc = combo & 3;
    const int rem = idx % 96;
    const int mg = rem / 24;         // [0,4)
    const int r2 = rem % 24;
    bx = r2 / 4;                     // [0,6)
    by = mg * 4 + (r2 & 3);          // [0,16)
  }
  const int m0 = by * 128;
  const int cz = cnt[z];
  if (m0 >= cz) return;
  const int n0 = bx * 128;
  constexpr int LD = PH ? 3072 : 768;
  const int kBeg = kc * 768;

  const int tid  = threadIdx.x;
  const int wave = tid >> 6;
  const int lane = tid & 63;
  const int wm = (wave >> 1) * 64;
  const int wn = (wave & 1) * 64;
  const int ln = lane & 15;
  const int kg = lane >> 4;
  const int rowA = lane >> 2;
  const int colK = (lane & 3) * 8;

  __shared__ short lds[24576];
  __shared__ int rows[128];
  __shared__ int rnks[128];
  if (tid < 128) {
    rows[tid] = list[z * 2048 + m0 + tid];
    if (PH == 1) rnks[tid] = rnkl[z * 2048 + m0 + tid];
  }

  f32x4 acc[4][4] = {};
  const bf16* Bz = Bp + (size_t)z * EB;

  for (int kt = kBeg; kt < kBeg + 768; kt += 32) {
    __syncthreads();
#pragma unroll
    for (int c2 = 0; c2 < 2; ++c2) {
      const int chunk = c2 * 4 + wave;
      const int r16 = chunk * 16 + rowA;
      const size_t arow =
          (PH == 0) ? (size_t)rows[r16] : (size_t)(z * 2048 + m0 + r16);
      const size_t brow = (size_t)(n0 + r16);
#pragma unroll
      for (int p = 0; p < 3; ++p) {
        gld16(Ap + (size_t)p * psA + arow * LD + kt + colK,
              &lds[p * 4096 + chunk * 512], lane);
        gld16(Bz + (size_t)p * psB + brow * LD + kt + colK,
              &lds[12288 + p * 4096 + chunk * 512], lane);
      }
    }
    __syncthreads();

    bf16x8 af[3][4];
#pragma unroll
    for (int r = 0; r < 4; ++r)
#pragma unroll
      for (int p = 0; p < 3; ++p)
        af[p][r] = *reinterpret_cast<const bf16x8*>(
            &lds[p * 4096 + (wm + r * 16 + ln) * 32 + kg * 8]);
    mfma6(acc, af, &lds[12288], wn, ln, kg);
  }

#pragma unroll
  for (int c = 0; c < 4; ++c) {
    const int col = n0 + wn + c * 16 + ln;
    float bvl = 0.f;
    if constexpr (PH == 0) bvl = b1z[z * 3072 + col];
#pragma unroll
    for (int r = 0; r < 4; ++r)
#pragma unroll
      for (int j = 0; j < 4; ++j) {
        const int rl = wm + r * 16 + kg * 4 + j;
        if constexpr (PH == 0) {
          const int pos = m0 + rl;
          const int tok = rows[rl];
          const float s = srow[tok * 4 + z];
          const float h = s * gelu(acc[r][c][j] + bvl);
          unsigned short u0, u1, u2;
          split3u(h, u0, u1, u2);
          unsigned short* hp = (unsigned short*)hseP;
          const size_t o = ((size_t)z * 2048 + pos) * 3072 + col;
          hp[o] = u0;
          hp[PSH + o] = u1;
          hp[2 * PSH + o] = u2;
        } else {
          if (m0 + rl < cz) {
            const int tok = rows[rl];
            const int rk = rnks[rl];
            xc[((size_t)(kc * 2 + rk) * T + tok) * 768 + col] = acc[r][c][j];
          }
        }
      }
  }
}

// ----------------------------------------------------- bf16 MFMA head GEMM --
__global__ __launch_bounds__(256) void k_bgemm(
    const bf16* __restrict__ A, const bf16* __restrict__ BT,
    const float* __restrict__ bias, float* __restrict__ outp,
    int ldc, int Keff) {
  const int tid  = threadIdx.x;
  const int wave = tid >> 6;
  const int lane = tid & 63;
  const int m0 = blockIdx.y * 128;
  const int n0 = blockIdx.x * 128;
  const int wm = (wave >> 1) * 64;
  const int wn = (wave & 1) * 64;
  const int ln = lane & 15;
  const int kg = lane >> 4;

  __shared__ short lds[8192];

  f32x4 acc[4][4] = {};

  const int rowA = lane >> 2;
  const int colK = (lane & 3) * 8;

  for (int kt = 0; kt < Keff; kt += 32) {
    __syncthreads();
#pragma unroll
    for (int c2 = 0; c2 < 2; ++c2) {
      const int chunk = c2 * 4 + wave;
      const int row = chunk * 16 + rowA;
      gld16(A + (size_t)(m0 + row) * 768 + kt + colK, &lds[chunk * 512], lane);
      gld16(BT + (size_t)(n0 + row) * 768 + kt + colK, &lds[4096 + chunk * 512],
            lane);
    }
    __syncthreads();

    bf16x8 af[4], bv[4];
#pragma unroll
    for (int r = 0; r < 4; ++r)
      af[r] = *reinterpret_cast<const bf16x8*>(
          &lds[(wm + r * 16 + ln) * 32 + kg * 8]);
#pragma unroll
    for (int c = 0; c < 4; ++c)
      bv[c] = *reinterpret_cast<const bf16x8*>(
          &lds[4096 + (wn + c * 16 + ln) * 32 + kg * 8]);

#pragma unroll
    for (int r = 0; r < 4; ++r)
#pragma unroll
      for (int c = 0; c < 4; ++c)
        acc[r][c] = __builtin_amdgcn_mfma_f32_16x16x32_bf16(
            af[r], bv[c], acc[r][c], 0, 0, 0);
  }

#pragma unroll
  for (int c = 0; c < 4; ++c) {
    const int nn = n0 + wn + c * 16 + ln;
    const float bvl = bias[nn];
#pragma unroll
    for (int r = 0; r < 4; ++r)
#pragma unroll
      for (int j = 0; j < 4; ++j) {
        const int mm = m0 + wm + r * 16 + kg * 4 + j;
        outp[(size_t)mm * ldc + nn] = acc[r][c][j] + bvl;
      }
  }
}

// -------------------------------------------------------------- transposes ---
// fp32 [R][C] -> bf16 [C][R] (head weights)
__global__ __launch_bounds__(256) void k_transpose(
    const float* __restrict__ in, unsigned short* __restrict__ out,
    int C, int outStride) {
  __shared__ float t[64][65];
  const int tx = threadIdx.x & 15, ty = threadIdx.x >> 4;
  const int r0 = blockIdx.y * 64, c0 = blockIdx.x * 64;
#pragma unroll
  for (int i = 0; i < 4; ++i) {
    const int r = ty + i * 16;
    const float4 v = *(const float4*)&in[(size_t)(r0 + r) * C + c0 + tx * 4];
    t[r][tx * 4 + 0] = v.x;
    t[r][tx * 4 + 1] = v.y;
    t[r][tx * 4 + 2] = v.z;
    t[r][tx * 4 + 3] = v.w;
  }
  __syncthreads();
#pragma unroll
  for (int i = 0; i < 4; ++i) {
    const int a = ty + i * 16;
    ushort4 v;
    v.x = f2bu(t[tx * 4 + 0][a]);
    v.y = f2bu(t[tx * 4 + 1][a]);
    v.z = f2bu(t[tx * 4 + 2][a]);
    v.w = f2bu(t[tx * 4 + 3][a]);
    *(ushort4*)&out[(size_t)(c0 + a) * outStride + r0 + tx * 4] = v;
  }
}

// fp32 [R][C] -> 3x bf16 planes [C][R], z batches (experts).
__global__ __launch_bounds__(256) void k_tsplit3(
    const float* __restrict__ in, long inE,
    unsigned short* __restrict__ out, long outE, long planeS,
    int C, int outStride) {
  in += (size_t)blockIdx.z * inE;
  unsigned short* o = out + (size_t)blockIdx.z * outE;
  __shared__ float t[64][65];
  const int tx = threadIdx.x & 15, ty = threadIdx.x >> 4;
  const int r0 = blockIdx.y * 64, c0 = blockIdx.x * 64;
#pragma unroll
  for (int i = 0; i < 4; ++i) {
    const int r = ty + i * 16;
    const float4 v = *(const float4*)&in[(size_t)(r0 + r) * C + c0 + tx * 4];
    t[r][tx * 4 + 0] = v.x;
    t[r][tx * 4 + 1] = v.y;
    t[r][tx * 4 + 2] = v.z;
    t[r][tx * 4 + 3] = v.w;
  }
  __syncthreads();
#pragma unroll
  for (int i = 0; i < 4; ++i) {
    const int a = ty + i * 16;
    ushort4 u0, u1, u2;
    split3u(t[tx * 4 + 0][a], u0.x, u1.x, u2.x);
    split3u(t[tx * 4 + 1][a], u0.y, u1.y, u2.y);
    split3u(t[tx * 4 + 2][a], u0.z, u1.z, u2.z);
    split3u(t[tx * 4 + 3][a], u0.w, u1.w, u2.w);
    const size_t off = (size_t)(c0 + a) * outStride + r0 + tx * 4;
    *(ushort4*)&o[off] = u0;
    *(ushort4*)&o[planeS + off] = u1;
    *(ushort4*)&o[2 * planeS + off] = u2;
  }
}

// ------------------------------------------------------------ small kernels --
__global__ void k_embed(const int* __restrict__ tok,
                        const float* __restrict__ emb,
                        const float* __restrict__ pos, float* __restrict__ x) {
  const int idx = blockIdx.x * 256 + threadIdx.x;
  const int t = idx / D, d = idx - t * D;
  const int tk = tok[t];
  x[idx] = emb[(size_t)tk * D + d] + pos[(size_t)(t & (L - 1)) * D + d];
}

__global__ void k_f2b(const float* __restrict__ x, bf16* __restrict__ o) {
  const int idx = blockIdx.x * 256 + threadIdx.x;
  o[idx] = f2b(x[idx]);
}

// LayerNorm fp32 in -> 3x bf16 planes out; optional fp32 gate logits (+gb).
__global__ __launch_bounds__(256) void k_ln(const float* __restrict__ x,
                                            const float* __restrict__ g,
                                            const float* __restrict__ bb,
                                            unsigned short* __restrict__ xnp,
                                            const float* __restrict__ gw,
                                            const float* __restrict__ gb,
                                            float* __restrict__ glog) {
  const int row = blockIdx.x, tid = threadIdx.x;
  const float* xr = x + (size_t)row * D;
  const float v0 = xr[tid], v1 = xr[tid + 256], v2 = xr[tid + 512];
  float s = v0 + v1 + v2, s2 = v0 * v0 + v1 * v1 + v2 * v2;
  for (int off = 1; off < 64; off <<= 1) {
    s += __shfl_xor(s, off);
    s2 += __shfl_xor(s2, off);
  }
  __shared__ float rs[4], rs2[4];
  const int w = tid >> 6;
  if ((tid & 63) == 0) { rs[w] = s; rs2[w] = s2; }
  __syncthreads();
  const float S = rs[0] + rs[1] + rs[2] + rs[3];
  const float S2 = rs2[0] + rs2[1] + rs2[2] + rs2[3];
  const float mean = S * (1.f / 768.f);
  const float var = fmaxf(S2 * (1.f / 768.f) - mean * mean, 0.f);
  const float rstd = rsqrtf(var + 1e-5f);
  const float o0 = (v0 - mean) * rstd * g[tid]       + bb[tid];
  const float o1 = (v1 - mean) * rstd * g[tid + 256] + bb[tid + 256];
  const float o2 = (v2 - mean) * rstd * g[tid + 512] + bb[tid + 512];
  {
    const size_t base = (size_t)row * D;
    unsigned short a0, a1, a2;
    split3u(o0, a0, a1, a2);
    xnp[base + tid] = a0;
    xnp[PSX + base + tid] = a1;
    xnp[2 * PSX + base + tid] = a2;
    split3u(o1, a0, a1, a2);
    xnp[base + tid + 256] = a0;
    xnp[PSX + base + tid + 256] = a1;
    xnp[2 * PSX + base + tid + 256] = a2;
    split3u(o2, a0, a1, a2);
    xnp[base + tid + 512] = a0;
    xnp[PSX + base + tid + 512] = a1;
    xnp[2 * PSX + base + tid + 512] = a2;
  }

  if (gw != nullptr) {
    const float4 ga = *(const float4*)&gw[tid * 4];
    const float4 gbv = *(const float4*)&gw[(tid + 256) * 4];
    const float4 gc = *(const float4*)&gw[(tid + 512) * 4];
    float p0 = o0 * ga.x + o1 * gbv.x + o2 * gc.x;
    float p1 = o0 * ga.y + o1 * gbv.y + o2 * gc.y;
    float p2 = o0 * ga.z + o1 * gbv.z + o2 * gc.z;
    float p3 = o0 * ga.w + o1 * gbv.w + o2 * gc.w;
    for (int off = 1; off < 64; off <<= 1) {
      p0 += __shfl_xor(p0, off);
      p1 += __shfl_xor(p1, off);
      p2 += __shfl_xor(p2, off);
      p3 += __shfl_xor(p3, off);
    }
    __shared__ float rg[4][4];
    if ((tid & 63) == 0) {
      rg[w][0] = p0; rg[w][1] = p1; rg[w][2] = p2; rg[w][3] = p3;
    }
    __syncthreads();
    if (tid == 0) {
      float* gl = glog + (size_t)row * 4;
#pragma unroll
      for (int e = 0; e < 4; ++e)
        gl[e] = rg[0][e] + rg[1][e] + rg[2][e] + rg[3][e] + gb[e];
    }
  }
}

// top-2 softmax weights + deterministic per-expert token lists.
__global__ __launch_bounds__(256) void k_scan(const float* __restrict__ glog,
                                              float* __restrict__ srow,
                                              int* __restrict__ list,
                                              int* __restrict__ rnkl,
                                              int* __restrict__ cnt) {
  const int tid = threadIdx.x;
  __shared__ unsigned char e1s[2048], e2s[2048];
  for (int t = tid; t < T; t += 256) {
    float gv[4];
#pragma unroll
    for (int i = 0; i < 4; ++i) gv[i] = glog[t * 4 + i];
    int i1 = 0;
#pragma unroll
    for (int i = 1; i < 4; ++i)
      if (gv[i] > gv[i1]) i1 = i;
    int i2 = -1;
#pragma unroll
    for (int i = 0; i < 4; ++i) {
      if (i == i1) continue;
      if (i2 < 0 || gv[i] > gv[i2]) i2 = i;
    }
    const float e = expf(gv[i2] - gv[i1]);
    const float wa = 1.f / (1.f + e), wb = e / (1.f + e);
    float o[4] = {0.f, 0.f, 0.f, 0.f};
    o[i1] = wa;
    o[i2] = wb;
#pragma unroll
    for (int i = 0; i < 4; ++i) srow[t * 4 + i] = o[i];
    e1s[t] = (unsigned char)i1;
    e2s[t] = (unsigned char)i2;
  }
  __syncthreads();
  const int w = tid >> 6, lane = tid & 63;
  int base = 0;
  for (int c = 0; c < 32; ++c) {
    const int t = c * 64 + lane;
    const bool f1 = (e1s[t] == w);
    const bool f2 = (e2s[t] == w);
    const bool f = f1 || f2;
    const unsigned long long mask = __ballot(f);
    const int mypos = __popcll(mask & ((1ull << lane) - 1ull));
    if (f) {
      list[w * 2048 + base + mypos] = t;
      rnkl[w * 2048 + base + mypos] = f1 ? 0 : 1;
    }
    base += __popcll(mask);
  }
  if (lane == 0) cnt[w] = base;
  for (int ppos = base + lane; ppos < 2048; ppos += 64) {
    list[w * 2048 + ppos] = 0;
    rnkl[w * 2048 + ppos] = 0;
  }
}

// x += sum_{c=0..7} xc[c] + sum_e srow[t][e] * b2[e][n]  (fixed order)
__global__ void k_moeadd(float* __restrict__ x, const float* __restrict__ xc,
                         const float* __restrict__ srow,
                         const float* __restrict__ b2l) {
  const int idx = blockIdx.x * 256 + threadIdx.x;
  const int t = idx / D, n = idx - t * D;
  const float* s = srow + t * 4;
  float acc = x[idx];
#pragma unroll
  for (int c = 0; c < 8; ++c) acc += xc[(size_t)c * T * D + idx];
  acc += s[0] * b2l[n] + s[1] * b2l[D + n] + s[2] * b2l[2 * D + n] +
         s[3] * b2l[3 * D + n];
  x[idx] = acc;
}

__global__ void k_cat3(const float* __restrict__ a, const float* __restrict__ b,
                       const float* __restrict__ c, float* __restrict__ o) {
  const int i = blockIdx.x * 256 + threadIdx.x;
  o[i] = i < 768 ? a[i] : (i < 1536 ? b[i - 768] : c[i - 1536]);
}

// Partial KV/Z over an L-chunk of 128 rows. part[c][bh][e*64+f], Z at +4096.
__global__ __launch_bounds__(256) void k_kvpart(const float* __restrict__ qkv,
                                                float* __restrict__ part) {
  const int bh = blockIdx.x;
  const int b = bh / NH, h = bh % NH;
  const int c = blockIdx.y;
  const int tid = threadIdx.x;
  __shared__ float kf[64], vv[64];
  float acc[16];
#pragma unroll
  for (int j = 0; j < 16; ++j) acc[j] = 0.f;
  float zacc = 0.f;
  const int e = tid >> 2;
  const int f0 = (tid & 3) * 16;
  const int t0 = b * L + c * 128;
  for (int i = 0; i < 128; ++i) {
    __syncthreads();
    const size_t rowb = (size_t)(t0 + i) * 2304;
    if (tid < 64) kf[tid] = qkv[rowb + 768 + h * 64 + tid];
    else if (tid < 128) vv[tid - 64] = qkv[rowb + 1536 + h * 64 + (tid - 64)];
    __syncthreads();
    const float ke = kf[e];
#pragma unroll
    for (int j = 0; j < 16; ++j) acc[j] += ke * vv[f0 + j];
    if (tid < 64) zacc += kf[tid];
  }
  const size_t base = ((size_t)c * 24 + bh) * 4160;
#pragma unroll
  for (int j = 0; j < 16; ++j) part[base + e * 64 + f0 + j] = acc[j];
  if (tid < 64) part[base + 4096 + tid] = zacc;
}

__global__ void k_kvred(const float* __restrict__ part, float* __restrict__ kv) {
  const int idx = blockIdx.x * 256 + threadIdx.x;
  float s = 0.f;
#pragma unroll
  for (int cc = 0; cc < 8; ++cc) s += part[(size_t)cc * 99840 + idx];
  kv[idx] = s;
}

// attention apply; emits 3-plane bf16x3 output for the o-proj g3 GEMM.
__global__ __launch_bounds__(256) void k_attnout(
    const float* __restrict__ qkv, const float* __restrict__ kv,
    unsigned short* __restrict__ attP) {
  const int t = blockIdx.x;
  const int b = t >> 10;
  const int tid = threadIdx.x;
  __shared__ float q[768];
  __shared__ float den[12];
  for (int i = tid; i < 768; i += 256) q[i] = qkv[(size_t)t * 2304 + i];
  __syncthreads();
  if (tid < 12) {
    const float* zz = kv + ((size_t)(b * NH + tid)) * 4160 + 4096;
    float s = 0.f;
#pragma unroll
    for (int e = 0; e < 64; ++e) s += q[tid * 64 + e] * zz[e];
    den[tid] = s + 1e-6f;
  }
  __syncthreads();
  for (int i = tid; i < 768; i += 256) {
    const int h = i >> 6, f = i & 63;
    const float* Kv = kv + ((size_t)(b * NH + h)) * 4160;
    float s = 0.f;
#pragma unroll
    for (int e = 0; e < 64; ++e) s += q[h * 64 + e] * Kv[e * 64 + f];
    const float r = s / den[h];
    unsigned short u0, u1, u2;
    split3u(r, u0, u1, u2);
    const size_t o = (size_t)t * 768 + i;
    attP[o] = u0;
    attP[PSX + o] = u1;
    attP[2 * PSX + o] = u2;
  }
}

// ------------------------------------------------------------------ launch ---
extern "C" void kernel_launch(void* const* d_in, const int* in_sizes, int n_in,
                              void* d_out, int out_size, void* d_ws,
                              size_t ws_size, hipStream_t stream) {
  const int*   tokens = (const int*)d_in[0];
  const float* emb  = (const float*)d_in[1];
  const float* pos  = (const float*)d_in[2];
  const float* qw   = (const float*)d_in[3];
  const float* qb   = (const float*)d_in[4];
  const float* kw   = (const float*)d_in[5];
  const float* kb   = (const float*)d_in[6];
  const float* vw   = (const float*)d_in[7];
  const float* vb   = (const float*)d_in[8];
  const float* ow   = (const float*)d_in[9];
  const float* ob   = (const float*)d_in[10];
  const float* ln1g = (const float*)d_in[11];
  const float* ln1b = (const float*)d_in[12];
  const float* ln2g = (const float*)d_in[13];
  const float* ln2b = (const float*)d_in[14];
  const float* gw   = (const float*)d_in[15];
  const float* gb   = (const float*)d_in[16];
  const float* w1   = (const float*)d_in[17];
  const float* b1   = (const float*)d_in[18];
  const float* w2   = (const float*)d_in[19];
  const float* b2   = (const float*)d_in[20];
  const float* hw   = (const float*)d_in[21];
  const float* hb   = (const float*)d_in[22];

  char* p = (char*)d_ws;
  auto alloc = [&](size_t bytes) -> void* {
    void* r = (void*)p;
    p += (bytes + 255) & ~((size_t)255);
    return r;
  };
  float* x    = (float*)alloc((size_t)T * D * 4);          // 6.3 MB
  float* xn   = (float*)alloc((size_t)T * D * 4);          // 6.3 MB (head xb)
  float* qkvb = (float*)alloc((size_t)T * 2304 * 4);       // 18.9 MB
  float* att  = (float*)alloc((size_t)T * D * 4);          // 6.3 MB \ pbuf
  float* kvp  = (float*)alloc((size_t)8 * 24 * 4160 * 4);  // 3.2 MB / 9.49 MB
  float* kv   = (float*)alloc((size_t)24 * 4160 * 4);
  float* srow = (float*)alloc((size_t)T * 4 * 4);
  float* glog = (float*)alloc((size_t)T * 4 * 4);
  float* bqkv = (float*)alloc((size_t)2304 * 4);
  int*   list = (int*)alloc((size_t)NE * 2048 * 4);
  int*   rnkl = (int*)alloc((size_t)NE * 2048 * 4);
  int*   cnt  = (int*)alloc((size_t)16);
  // Shared activation-plane buffer (3 x T x 768 bf16 = 9.44 MB) overlays
  // att+kvp (9.49 MB; strict sequential reuse per phase).
  unsigned short* pbuf = (unsigned short*)att;
  // d_out (262.1 MB) scratch overlays, all dead before the head writes it:
  //   hseP @0: 3 planes x [4][2048][3072] bf16 = 151.0 MB
  //   xc   @151.0: 8 fp32 buffers x [T][768]   =  50.3 MB
  //   wp   @201.3: weight planes slot          <= 56.6 MB
  bf16* hseP = (bf16*)d_out;
  float* xc = (float*)((char*)d_out + (size_t)3 * PSH * 2);
  unsigned short* wp =
      (unsigned short*)((char*)d_out + (size_t)3 * PSH * 2 +
                        (size_t)8 * T * D * 4);
  unsigned short* wqkvP = wp;                       // 3 planes x [2304][768]
  unsigned short* owP   = wp + (size_t)3 * PSQ;     // 3 planes x [768][768]
  // Head-phase overlays (dead regions): xb on xn; hwT on qkvb+att.
  bf16* xb  = (bf16*)xn;
  bf16* hwT = (bf16*)qkvb;

  k_embed<<<dim3(6144), 256, 0, stream>>>(tokens, emb, pos, x);

  for (int l = 0; l < NL; ++l) {
    const size_t DD = (size_t)D * D;
    // attention weight planes: qw/kw/vw -> wqkvP rows 0/768/1536; ow -> owP
    k_tsplit3<<<dim3(12, 12, 1), 256, 0, stream>>>(qw + l * DD, 0, wqkvP, 0,
                                                   PSQ, D, D);
    k_tsplit3<<<dim3(12, 12, 1), 256, 0, stream>>>(
        kw + l * DD, 0, wqkvP + (size_t)768 * 768, 0, PSQ, D, D);
    k_tsplit3<<<dim3(12, 12, 1), 256, 0, stream>>>(
        vw + l * DD, 0, wqkvP + (size_t)1536 * 768, 0, PSQ, D, D);
    k_tsplit3<<<dim3(12, 12, 1), 256, 0, stream>>>(ow + l * DD, 0, owP, 0,
                                                   PSO, D, D);
    k_cat3<<<dim3(9), 256, 0, stream>>>(qb + l * D, kb + l * D, vb + l * D,
                                        bqkv);

    // attention (bf16x3 fp32-faithful GEMMs)
    k_ln<<<dim3(T), 256, 0, stream>>>(x, ln1g + l * D, ln1b + l * D, pbuf,
                                      nullptr, nullptr, nullptr);
    k_g3<1><<<dim3(18, 16, 1), 256, 0, stream>>>(
        (const bf16*)pbuf, PSX, (const bf16*)wqkvP, PSQ, bqkv, qkvb, 2304);
    k_kvpart<<<dim3(24, 8), 256, 0, stream>>>(qkvb, kvp);
    k_kvred<<<dim3(390), 256, 0, stream>>>(kvp, kv);
    k_attnout<<<dim3(T), 256, 0, stream>>>(qkvb, kv, pbuf);
    k_g3<2><<<dim3(6, 16, 1), 256, 0, stream>>>(
        (const bf16*)pbuf, PSX, (const bf16*)owP, PSO, ob + l * D, x, D);

    // MoE (sparse top-2, bf16x3 MFMA; XCD-resident schedules)
    k_ln<<<dim3(T), 256, 0, stream>>>(x, ln2g + l * D, ln2b + l * D, pbuf,
                                      gw + (size_t)l * D * NE, gb + l * NE,
                                      glog);
    k_scan<<<dim3(1), 256, 0, stream>>>(glog, srow, list, rnkl, cnt);
    k_tsplit3<<<dim3(48, 12, 4), 256, 0, stream>>>(
        w1 + (size_t)l * NE * D * DH, (long)D * DH, wp, EB, PSW, DH, D);
    k_moe3<0><<<dim3(24, 16, 4), 256, 0, stream>>>(
        (const bf16*)pbuf, PSX, (const bf16*)wp, PSW, b1 + (size_t)l * NE * DH,
        hseP, nullptr, srow, list, rnkl, cnt);
    k_tsplit3<<<dim3(12, 48, 4), 256, 0, stream>>>(
        w2 + (size_t)l * NE * DH * D, (long)DH * D, wp, EB, PSW, D, DH);
    k_moe3<1><<<dim3(6, 16, 16), 256, 0, stream>>>(
        hseP, PSH, (const bf16*)wp, PSW, nullptr, nullptr, xc, srow, list,
        rnkl, cnt);
    k_moeadd<<<dim3(6144), 256, 0, stream>>>(x, xc, srow,
                                             b2 + (size_t)l * NE * D);
  }

  // ------------------------------------------------------------- head -------
  k_f2b<<<dim3(6144), 256, 0, stream>>>(x, xb);
  for (int half = 0; half < 2; ++half) {
    k_transpose<<<dim3(250, 12, 1), 256, 0, stream>>>(
        hw + half * 16000, (unsigned short*)hwT, V, D);
    k_bgemm<<<dim3(125, 16, 1), 256, 0, stream>>>(
        xb, hwT, hb + half * 16000, (float*)d_out + half * 16000, V, D);
  }
}

// Round 14
// 1983.213 us; speedup vs baseline: 1.4313x; 1.4313x over previous
//
#include <hip/hip_runtime.h>
#include <hip/hip_bf16.h>
#include <cstdint>
#include <cstddef>

typedef __hip_bfloat16 bf16;
typedef __attribute__((ext_vector_type(8))) short bf16x8;
typedef __attribute__((ext_vector_type(4))) float f32x4;

#define DEV __device__ __forceinline__

static constexpr int D  = 768;
static constexpr int NH = 12;
static constexpr int NE = 4;
static constexpr int DH = 3072;
static constexpr int L  = 1024;
static constexpr int T  = 2048;
static constexpr int V  = 32000;
static constexpr int NL = 4;

static constexpr long PSX = (long)T * 768;        // activation plane stride
static constexpr long PSH = (long)NE * 2048 * DH; // hse plane stride
static constexpr long PSW = (long)NE * DH * 768;  // MoE weight plane stride
static constexpr long PSQ = (long)2304 * 768;     // qkv weight plane stride
static constexpr long PSO = (long)768 * 768;      // o-proj weight plane stride
static constexpr long EB  = (long)DH * 768;       // per-expert weight elems

DEV float b2f(bf16 v) { return __bfloat162float(v); }
DEV bf16 f2b(float f) { return __float2bfloat16(f); }
DEV unsigned short f2bu(float f) {
  bf16 b = f2b(f);
  return *reinterpret_cast<unsigned short*>(&b);
}
DEV float gelu(float v) {
  return 0.5f * v * (1.f + erff(v * 0.70710678118654752f));
}
// fp32 -> 2x bf16 planes (a ~= p0+p1 to ~2^-18 rel; dropped a1*b1 cross term
// also ~2^-18 -> GEMM rel error ~1e-5, 2^9 x smaller than the bf16 noise that
// flipped top-2 routing in r1-r4).
DEV void split2u(float a, unsigned short& x0, unsigned short& x1) {
  bf16 c0 = f2b(a);
  float r1 = a - b2f(c0);
  bf16 c1 = f2b(r1);
  x0 = *reinterpret_cast<unsigned short*>(&c0);
  x1 = *reinterpret_cast<unsigned short*>(&c1);
}

// ---------------------------------------------------------------- staging ----
DEV void gld16(const void* g, short* ldsbase, int lane) {
#if __has_builtin(__builtin_amdgcn_global_load_lds)
  (void)lane;
  __builtin_amdgcn_global_load_lds(
      (const __attribute__((address_space(1))) unsigned int*)g,
      (__attribute__((address_space(3))) unsigned int*)ldsbase, 16, 0, 0);
#else
  *reinterpret_cast<bf16x8*>(ldsbase + lane * 8) =
      *reinterpret_cast<const bf16x8*>(g);
#endif
}

// 3-term bf16x2 MFMA accumulate helper (a0b0 + a0b1 + a1b0).
DEV void mfma3(f32x4 acc[4][4], const bf16x8 af[2][4], const short* ldsB,
               int wn, int ln, int kg) {
#pragma unroll
  for (int c = 0; c < 4; ++c) {
    const int bo = (wn + c * 16 + ln) * 32 + kg * 8;
    const bf16x8 bv0 = *reinterpret_cast<const bf16x8*>(&ldsB[bo]);
    const bf16x8 bv1 = *reinterpret_cast<const bf16x8*>(&ldsB[4096 + bo]);
#pragma unroll
    for (int r = 0; r < 4; ++r) {
      f32x4 a = acc[r][c];
      a = __builtin_amdgcn_mfma_f32_16x16x32_bf16(af[1][r], bv0, a, 0, 0, 0);
      a = __builtin_amdgcn_mfma_f32_16x16x32_bf16(af[0][r], bv1, a, 0, 0, 0);
      a = __builtin_amdgcn_mfma_f32_16x16x32_bf16(af[0][r], bv0, a, 0, 0, 0);
      acc[r][c] = a;
    }
  }
}

// --------------------------------------- dense bf16x2 fp32-faithful GEMM ----
// C[2048,N] = A @ B + bias; A planes [2048][768], B^T planes [N][768], K=768.
// EPI 1: qkv (elu+1 for col<1536) -> fp32 out. EPI 2: out += acc + bias.
template <int EPI>
__global__ __launch_bounds__(256) void k_g3(
    const bf16* __restrict__ Ap, long psA,
    const bf16* __restrict__ Bp, long psB,
    const float* __restrict__ bias,
    float* __restrict__ outp, int ldc) {
  const int m0 = blockIdx.y * 128;
  const int n0 = blockIdx.x * 128;
  const int tid  = threadIdx.x;
  const int wave = tid >> 6;
  const int lane = tid & 63;
  const int wm = (wave >> 1) * 64;
  const int wn = (wave & 1) * 64;
  const int ln = lane & 15;
  const int kg = lane >> 4;
  const int rowA = lane >> 2;
  const int colK = (lane & 3) * 8;

  __shared__ short lds[16384];  // A planes @0/4096, B planes @8192/12288

  f32x4 acc[4][4] = {};

  for (int kt = 0; kt < 768; kt += 32) {
    __syncthreads();
#pragma unroll
    for (int c2 = 0; c2 < 2; ++c2) {
      const int chunk = c2 * 4 + wave;
      const int r16 = chunk * 16 + rowA;
      const size_t arow = (size_t)(m0 + r16);
      const size_t brow = (size_t)(n0 + r16);
#pragma unroll
      for (int p = 0; p < 2; ++p) {
        gld16(Ap + (size_t)p * psA + arow * 768 + kt + colK,
              &lds[p * 4096 + chunk * 512], lane);
        gld16(Bp + (size_t)p * psB + brow * 768 + kt + colK,
              &lds[8192 + p * 4096 + chunk * 512], lane);
      }
    }
    __syncthreads();

    bf16x8 af[2][4];
#pragma unroll
    for (int r = 0; r < 4; ++r)
#pragma unroll
      for (int p = 0; p < 2; ++p)
        af[p][r] = *reinterpret_cast<const bf16x8*>(
            &lds[p * 4096 + (wm + r * 16 + ln) * 32 + kg * 8]);
    mfma3(acc, af, &lds[8192], wn, ln, kg);
  }

#pragma unroll
  for (int c = 0; c < 4; ++c) {
    const int col = n0 + wn + c * 16 + ln;
    const float bvl = bias[col];
#pragma unroll
    for (int r = 0; r < 4; ++r)
#pragma unroll
      for (int j = 0; j < 4; ++j) {
        const int row = m0 + wm + r * 16 + kg * 4 + j;
        const float v = acc[r][c][j] + bvl;
        const size_t idx = (size_t)row * ldc + col;
        if constexpr (EPI == 1) {
          outp[idx] = (col < 1536) ? (v > 0.f ? v + 1.f : expf(v)) : v;
        } else {
          outp[idx] += v;
        }
      }
  }
}

// ----------------------------------------- bf16x2 split-precision MoE GEMM --
// PH=0 (UP):  grid (24,16,4), flat mapping (r13 XCD-resident schedule cut
//             fetch 6x but regressed time -> kernel is MFMA/latency-bound).
//             Gather rows via list[z]; out = hse planes (gelu*srow, split2).
// PH=1 (DOWN):grid (6,16,16); blockIdx.z = z*4+kc (split-K 3072 = 4x768);
//             out xc[(kc*2+rank)][tok][768] fp32.
template <int PH>
__global__ __launch_bounds__(256) void k_moe3(
    const bf16* __restrict__ Ap, long psA,
    const bf16* __restrict__ Bp, long psB,
    const float* __restrict__ b1z,
    bf16* __restrict__ hseP,
    float* __restrict__ xc,
    const float* __restrict__ srow, const int* __restrict__ list,
    const int* __restrict__ rnkl, const int* __restrict__ cnt) {
  const int zz = blockIdx.z;
  const int z  = (PH == 0) ? zz : (zz >> 2);
  const int kc = (PH == 0) ? 0 : (zz & 3);
  const int m0 = blockIdx.y * 128;
  const int cz = cnt[z];
  if (m0 >= cz) return;
  const int n0 = blockIdx.x * 128;
  constexpr int LD = PH ? 3072 : 768;
  const int kBeg = kc * 768;

  const int tid  = threadIdx.x;
  const int wave = tid >> 6;
  const int lane = tid & 63;
  const int wm = (wave >> 1) * 64;
  const int wn = (wave & 1) * 64;
  const int ln = lane & 15;
  const int kg = lane >> 4;
  const int rowA = lane >> 2;
  const int colK = (lane & 3) * 8;

  __shared__ short lds[16384];
  __shared__ int rows[128];
  __shared__ int rnks[128];
  if (tid < 128) {
    rows[tid] = list[z * 2048 + m0 + tid];
    if (PH == 1) rnks[tid] = rnkl[z * 2048 + m0 + tid];
  }

  f32x4 acc[4][4] = {};
  const bf16* Bz = Bp + (size_t)z * EB;

  for (int kt = kBeg; kt < kBeg + 768; kt += 32) {
    __syncthreads();
#pragma unroll
    for (int c2 = 0; c2 < 2; ++c2) {
      const int chunk = c2 * 4 + wave;
      const int r16 = chunk * 16 + rowA;
      const size_t arow =
          (PH == 0) ? (size_t)rows[r16] : (size_t)(z * 2048 + m0 + r16);
      const size_t brow = (size_t)(n0 + r16);
#pragma unroll
      for (int p = 0; p < 2; ++p) {
        gld16(Ap + (size_t)p * psA + arow * LD + kt + colK,
              &lds[p * 4096 + chunk * 512], lane);
        gld16(Bz + (size_t)p * psB + brow * LD + kt + colK,
              &lds[8192 + p * 4096 + chunk * 512], lane);
      }
    }
    __syncthreads();

    bf16x8 af[2][4];
#pragma unroll
    for (int r = 0; r < 4; ++r)
#pragma unroll
      for (int p = 0; p < 2; ++p)
        af[p][r] = *reinterpret_cast<const bf16x8*>(
            &lds[p * 4096 + (wm + r * 16 + ln) * 32 + kg * 8]);
    mfma3(acc, af, &lds[8192], wn, ln, kg);
  }

#pragma unroll
  for (int c = 0; c < 4; ++c) {
    const int col = n0 + wn + c * 16 + ln;
    float bvl = 0.f;
    if constexpr (PH == 0) bvl = b1z[z * 3072 + col];
#pragma unroll
    for (int r = 0; r < 4; ++r)
#pragma unroll
      for (int j = 0; j < 4; ++j) {
        const int rl = wm + r * 16 + kg * 4 + j;
        if constexpr (PH == 0) {
          const int pos = m0 + rl;
          const int tok = rows[rl];
          const float s = srow[tok * 4 + z];
          const float h = s * gelu(acc[r][c][j] + bvl);
          unsigned short u0, u1;
          split2u(h, u0, u1);
          unsigned short* hp = (unsigned short*)hseP;
          const size_t o = ((size_t)z * 2048 + pos) * 3072 + col;
          hp[o] = u0;
          hp[PSH + o] = u1;
        } else {
          if (m0 + rl < cz) {
            const int tok = rows[rl];
            const int rk = rnks[rl];
            xc[((size_t)(kc * 2 + rk) * T + tok) * 768 + col] = acc[r][c][j];
          }
        }
      }
  }
}

// ----------------------------------------------------- bf16 MFMA head GEMM --
__global__ __launch_bounds__(256) void k_bgemm(
    const bf16* __restrict__ A, const bf16* __restrict__ BT,
    const float* __restrict__ bias, float* __restrict__ outp,
    int ldc, int Keff) {
  const int tid  = threadIdx.x;
  const int wave = tid >> 6;
  const int lane = tid & 63;
  const int m0 = blockIdx.y * 128;
  const int n0 = blockIdx.x * 128;
  const int wm = (wave >> 1) * 64;
  const int wn = (wave & 1) * 64;
  const int ln = lane & 15;
  const int kg = lane >> 4;

  __shared__ short lds[8192];

  f32x4 acc[4][4] = {};

  const int rowA = lane >> 2;
  const int colK = (lane & 3) * 8;

  for (int kt = 0; kt < Keff; kt += 32) {
    __syncthreads();
#pragma unroll
    for (int c2 = 0; c2 < 2; ++c2) {
      const int chunk = c2 * 4 + wave;
      const int row = chunk * 16 + rowA;
      gld16(A + (size_t)(m0 + row) * 768 + kt + colK, &lds[chunk * 512], lane);
      gld16(BT + (size_t)(n0 + row) * 768 + kt + colK, &lds[4096 + chunk * 512],
            lane);
    }
    __syncthreads();

    bf16x8 af[4], bv[4];
#pragma unroll
    for (int r = 0; r < 4; ++r)
      af[r] = *reinterpret_cast<const bf16x8*>(
          &lds[(wm + r * 16 + ln) * 32 + kg * 8]);
#pragma unroll
    for (int c = 0; c < 4; ++c)
      bv[c] = *reinterpret_cast<const bf16x8*>(
          &lds[4096 + (wn + c * 16 + ln) * 32 + kg * 8]);

#pragma unroll
    for (int r = 0; r < 4; ++r)
#pragma unroll
      for (int c = 0; c < 4; ++c)
        acc[r][c] = __builtin_amdgcn_mfma_f32_16x16x32_bf16(
            af[r], bv[c], acc[r][c], 0, 0, 0);
  }

#pragma unroll
  for (int c = 0; c < 4; ++c) {
    const int nn = n0 + wn + c * 16 + ln;
    const float bvl = bias[nn];
#pragma unroll
    for (int r = 0; r < 4; ++r)
#pragma unroll
      for (int j = 0; j < 4; ++j) {
        const int mm = m0 + wm + r * 16 + kg * 4 + j;
        outp[(size_t)mm * ldc + nn] = acc[r][c][j] + bvl;
      }
  }
}

// -------------------------------------------------------------- transposes ---
// fp32 [R][C] -> bf16 [C][R] (head weights)
__global__ __launch_bounds__(256) void k_transpose(
    const float* __restrict__ in, unsigned short* __restrict__ out,
    int C, int outStride) {
  __shared__ float t[64][65];
  const int tx = threadIdx.x & 15, ty = threadIdx.x >> 4;
  const int r0 = blockIdx.y * 64, c0 = blockIdx.x * 64;
#pragma unroll
  for (int i = 0; i < 4; ++i) {
    const int r = ty + i * 16;
    const float4 v = *(const float4*)&in[(size_t)(r0 + r) * C + c0 + tx * 4];
    t[r][tx * 4 + 0] = v.x;
    t[r][tx * 4 + 1] = v.y;
    t[r][tx * 4 + 2] = v.z;
    t[r][tx * 4 + 3] = v.w;
  }
  __syncthreads();
#pragma unroll
  for (int i = 0; i < 4; ++i) {
    const int a = ty + i * 16;
    ushort4 v;
    v.x = f2bu(t[tx * 4 + 0][a]);
    v.y = f2bu(t[tx * 4 + 1][a]);
    v.z = f2bu(t[tx * 4 + 2][a]);
    v.w = f2bu(t[tx * 4 + 3][a]);
    *(ushort4*)&out[(size_t)(c0 + a) * outStride + r0 + tx * 4] = v;
  }
}

// fp32 [R][C] -> 2x bf16 planes [C][R], z batches (experts).
__global__ __launch_bounds__(256) void k_tsplit2(
    const float* __restrict__ in, long inE,
    unsigned short* __restrict__ out, long outE, long planeS,
    int C, int outStride) {
  in += (size_t)blockIdx.z * inE;
  unsigned short* o = out + (size_t)blockIdx.z * outE;
  __shared__ float t[64][65];
  const int tx = threadIdx.x & 15, ty = threadIdx.x >> 4;
  const int r0 = blockIdx.y * 64, c0 = blockIdx.x * 64;
#pragma unroll
  for (int i = 0; i < 4; ++i) {
    const int r = ty + i * 16;
    const float4 v = *(const float4*)&in[(size_t)(r0 + r) * C + c0 + tx * 4];
    t[r][tx * 4 + 0] = v.x;
    t[r][tx * 4 + 1] = v.y;
    t[r][tx * 4 + 2] = v.z;
    t[r][tx * 4 + 3] = v.w;
  }
  __syncthreads();
#pragma unroll
  for (int i = 0; i < 4; ++i) {
    const int a = ty + i * 16;
    ushort4 u0, u1;
    split2u(t[tx * 4 + 0][a], u0.x, u1.x);
    split2u(t[tx * 4 + 1][a], u0.y, u1.y);
    split2u(t[tx * 4 + 2][a], u0.z, u1.z);
    split2u(t[tx * 4 + 3][a], u0.w, u1.w);
    const size_t off = (size_t)(c0 + a) * outStride + r0 + tx * 4;
    *(ushort4*)&o[off] = u0;
    *(ushort4*)&o[planeS + off] = u1;
  }
}

// ------------------------------------------------------------ small kernels --
__global__ void k_embed(const int* __restrict__ tok,
                        const float* __restrict__ emb,
                        const float* __restrict__ pos, float* __restrict__ x) {
  const int idx = blockIdx.x * 256 + threadIdx.x;
  const int t = idx / D, d = idx - t * D;
  const int tk = tok[t];
  x[idx] = emb[(size_t)tk * D + d] + pos[(size_t)(t & (L - 1)) * D + d];
}

__global__ void k_f2b(const float* __restrict__ x, bf16* __restrict__ o) {
  const int idx = blockIdx.x * 256 + threadIdx.x;
  o[idx] = f2b(x[idx]);
}

// LayerNorm fp32 in -> 2x bf16 planes out; optional fp32 gate logits (+gb).
__global__ __launch_bounds__(256) void k_ln(const float* __restrict__ x,
                                            const float* __restrict__ g,
                                            const float* __restrict__ bb,
                                            unsigned short* __restrict__ xnp,
                                            const float* __restrict__ gw,
                                            const float* __restrict__ gb,
                                            float* __restrict__ glog) {
  const int row = blockIdx.x, tid = threadIdx.x;
  const float* xr = x + (size_t)row * D;
  const float v0 = xr[tid], v1 = xr[tid + 256], v2 = xr[tid + 512];
  float s = v0 + v1 + v2, s2 = v0 * v0 + v1 * v1 + v2 * v2;
  for (int off = 1; off < 64; off <<= 1) {
    s += __shfl_xor(s, off);
    s2 += __shfl_xor(s2, off);
  }
  __shared__ float rs[4], rs2[4];
  const int w = tid >> 6;
  if ((tid & 63) == 0) { rs[w] = s; rs2[w] = s2; }
  __syncthreads();
  const float S = rs[0] + rs[1] + rs[2] + rs[3];
  const float S2 = rs2[0] + rs2[1] + rs2[2] + rs2[3];
  const float mean = S * (1.f / 768.f);
  const float var = fmaxf(S2 * (1.f / 768.f) - mean * mean, 0.f);
  const float rstd = rsqrtf(var + 1e-5f);
  const float o0 = (v0 - mean) * rstd * g[tid]       + bb[tid];
  const float o1 = (v1 - mean) * rstd * g[tid + 256] + bb[tid + 256];
  const float o2 = (v2 - mean) * rstd * g[tid + 512] + bb[tid + 512];
  {
    const size_t base = (size_t)row * D;
    unsigned short a0, a1;
    split2u(o0, a0, a1);
    xnp[base + tid] = a0;
    xnp[PSX + base + tid] = a1;
    split2u(o1, a0, a1);
    xnp[base + tid + 256] = a0;
    xnp[PSX + base + tid + 256] = a1;
    split2u(o2, a0, a1);
    xnp[base + tid + 512] = a0;
    xnp[PSX + base + tid + 512] = a1;
  }

  if (gw != nullptr) {
    const float4 ga = *(const float4*)&gw[tid * 4];
    const float4 gbv = *(const float4*)&gw[(tid + 256) * 4];
    const float4 gc = *(const float4*)&gw[(tid + 512) * 4];
    float p0 = o0 * ga.x + o1 * gbv.x + o2 * gc.x;
    float p1 = o0 * ga.y + o1 * gbv.y + o2 * gc.y;
    float p2 = o0 * ga.z + o1 * gbv.z + o2 * gc.z;
    float p3 = o0 * ga.w + o1 * gbv.w + o2 * gc.w;
    for (int off = 1; off < 64; off <<= 1) {
      p0 += __shfl_xor(p0, off);
      p1 += __shfl_xor(p1, off);
      p2 += __shfl_xor(p2, off);
      p3 += __shfl_xor(p3, off);
    }
    __shared__ float rg[4][4];
    if ((tid & 63) == 0) {
      rg[w][0] = p0; rg[w][1] = p1; rg[w][2] = p2; rg[w][3] = p3;
    }
    __syncthreads();
    if (tid == 0) {
      float* gl = glog + (size_t)row * 4;
#pragma unroll
      for (int e = 0; e < 4; ++e)
        gl[e] = rg[0][e] + rg[1][e] + rg[2][e] + rg[3][e] + gb[e];
    }
  }
}

// top-2 softmax weights + deterministic per-expert token lists.
__global__ __launch_bounds__(256) void k_scan(const float* __restrict__ glog,
                                              float* __restrict__ srow,
                                              int* __restrict__ list,
                                              int* __restrict__ rnkl,
                                              int* __restrict__ cnt) {
  const int tid = threadIdx.x;
  __shared__ unsigned char e1s[2048], e2s[2048];
  for (int t = tid; t < T; t += 256) {
    float gv[4];
#pragma unroll
    for (int i = 0; i < 4; ++i) gv[i] = glog[t * 4 + i];
    int i1 = 0;
#pragma unroll
    for (int i = 1; i < 4; ++i)
      if (gv[i] > gv[i1]) i1 = i;
    int i2 = -1;
#pragma unroll
    for (int i = 0; i < 4; ++i) {
      if (i == i1) continue;
      if (i2 < 0 || gv[i] > gv[i2]) i2 = i;
    }
    const float e = expf(gv[i2] - gv[i1]);
    const float wa = 1.f / (1.f + e), wb = e / (1.f + e);
    float o[4] = {0.f, 0.f, 0.f, 0.f};
    o[i1] = wa;
    o[i2] = wb;
#pragma unroll
    for (int i = 0; i < 4; ++i) srow[t * 4 + i] = o[i];
    e1s[t] = (unsigned char)i1;
    e2s[t] = (unsigned char)i2;
  }
  __syncthreads();
  const int w = tid >> 6, lane = tid & 63;
  int base = 0;
  for (int c = 0; c < 32; ++c) {
    const int t = c * 64 + lane;
    const bool f1 = (e1s[t] == w);
    const bool f2 = (e2s[t] == w);
    const bool f = f1 || f2;
    const unsigned long long mask = __ballot(f);
    const int mypos = __popcll(mask & ((1ull << lane) - 1ull));
    if (f) {
      list[w * 2048 + base + mypos] = t;
      rnkl[w * 2048 + base + mypos] = f1 ? 0 : 1;
    }
    base += __popcll(mask);
  }
  if (lane == 0) cnt[w] = base;
  for (int ppos = base + lane; ppos < 2048; ppos += 64) {
    list[w * 2048 + ppos] = 0;
    rnkl[w * 2048 + ppos] = 0;
  }
}

// x += sum_{c=0..7} xc[c] + sum_e srow[t][e] * b2[e][n]  (fixed order)
__global__ void k_moeadd(float* __restrict__ x, const float* __restrict__ xc,
                         const float* __restrict__ srow,
                         const float* __restrict__ b2l) {
  const int idx = blockIdx.x * 256 + threadIdx.x;
  const int t = idx / D, n = idx - t * D;
  const float* s = srow + t * 4;
  float acc = x[idx];
#pragma unroll
  for (int c = 0; c < 8; ++c) acc += xc[(size_t)c * T * D + idx];
  acc += s[0] * b2l[n] + s[1] * b2l[D + n] + s[2] * b2l[2 * D + n] +
         s[3] * b2l[3 * D + n];
  x[idx] = acc;
}

__global__ void k_cat3(const float* __restrict__ a, const float* __restrict__ b,
                       const float* __restrict__ c, float* __restrict__ o) {
  const int i = blockIdx.x * 256 + threadIdx.x;
  o[i] = i < 768 ? a[i] : (i < 1536 ? b[i - 768] : c[i - 1536]);
}

// Partial KV/Z over an L-chunk of 128 rows. part[c][bh][e*64+f], Z at +4096.
__global__ __launch_bounds__(256) void k_kvpart(const float* __restrict__ qkv,
                                                float* __restrict__ part) {
  const int bh = blockIdx.x;
  const int b = bh / NH, h = bh % NH;
  const int c = blockIdx.y;
  const int tid = threadIdx.x;
  __shared__ float kf[64], vv[64];
  float acc[16];
#pragma unroll
  for (int j = 0; j < 16; ++j) acc[j] = 0.f;
  float zacc = 0.f;
  const int e = tid >> 2;
  const int f0 = (tid & 3) * 16;
  const int t0 = b * L + c * 128;
  for (int i = 0; i < 128; ++i) {
    __syncthreads();
    const size_t rowb = (size_t)(t0 + i) * 2304;
    if (tid < 64) kf[tid] = qkv[rowb + 768 + h * 64 + tid];
    else if (tid < 128) vv[tid - 64] = qkv[rowb + 1536 + h * 64 + (tid - 64)];
    __syncthreads();
    const float ke = kf[e];
#pragma unroll
    for (int j = 0; j < 16; ++j) acc[j] += ke * vv[f0 + j];
    if (tid < 64) zacc += kf[tid];
  }
  const size_t base = ((size_t)c * 24 + bh) * 4160;
#pragma unroll
  for (int j = 0; j < 16; ++j) part[base + e * 64 + f0 + j] = acc[j];
  if (tid < 64) part[base + 4096 + tid] = zacc;
}

__global__ void k_kvred(const float* __restrict__ part, float* __restrict__ kv) {
  const int idx = blockIdx.x * 256 + threadIdx.x;
  float s = 0.f;
#pragma unroll
  for (int cc = 0; cc < 8; ++cc) s += part[(size_t)cc * 99840 + idx];
  kv[idx] = s;
}

// attention apply; emits 2-plane bf16x2 output for the o-proj g3 GEMM.
__global__ __launch_bounds__(256) void k_attnout(
    const float* __restrict__ qkv, const float* __restrict__ kv,
    unsigned short* __restrict__ attP) {
  const int t = blockIdx.x;
  const int b = t >> 10;
  const int tid = threadIdx.x;
  __shared__ float q[768];
  __shared__ float den[12];
  for (int i = tid; i < 768; i += 256) q[i] = qkv[(size_t)t * 2304 + i];
  __syncthreads();
  if (tid < 12) {
    const float* zz = kv + ((size_t)(b * NH + tid)) * 4160 + 4096;
    float s = 0.f;
#pragma unroll
    for (int e = 0; e < 64; ++e) s += q[tid * 64 + e] * zz[e];
    den[tid] = s + 1e-6f;
  }
  __syncthreads();
  for (int i = tid; i < 768; i += 256) {
    const int h = i >> 6, f = i & 63;
    const float* Kv = kv + ((size_t)(b * NH + h)) * 4160;
    float s = 0.f;
#pragma unroll
    for (int e = 0; e < 64; ++e) s += q[h * 64 + e] * Kv[e * 64 + f];
    const float r = s / den[h];
    unsigned short u0, u1;
    split2u(r, u0, u1);
    const size_t o = (size_t)t * 768 + i;
    attP[o] = u0;
    attP[PSX + o] = u1;
  }
}

// ------------------------------------------------------------------ launch ---
extern "C" void kernel_launch(void* const* d_in, const int* in_sizes, int n_in,
                              void* d_out, int out_size, void* d_ws,
                              size_t ws_size, hipStream_t stream) {
  const int*   tokens = (const int*)d_in[0];
  const float* emb  = (const float*)d_in[1];
  const float* pos  = (const float*)d_in[2];
  const float* qw   = (const float*)d_in[3];
  const float* qb   = (const float*)d_in[4];
  const float* kw   = (const float*)d_in[5];
  const float* kb   = (const float*)d_in[6];
  const float* vw   = (const float*)d_in[7];
  const float* vb   = (const float*)d_in[8];
  const float* ow   = (const float*)d_in[9];
  const float* ob   = (const float*)d_in[10];
  const float* ln1g = (const float*)d_in[11];
  const float* ln1b = (const float*)d_in[12];
  const float* ln2g = (const float*)d_in[13];
  const float* ln2b = (const float*)d_in[14];
  const float* gw   = (const float*)d_in[15];
  const float* gb   = (const float*)d_in[16];
  const float* w1   = (const float*)d_in[17];
  const float* b1   = (const float*)d_in[18];
  const float* w2   = (const float*)d_in[19];
  const float* b2   = (const float*)d_in[20];
  const float* hw   = (const float*)d_in[21];
  const float* hb   = (const float*)d_in[22];

  char* p = (char*)d_ws;
  auto alloc = [&](size_t bytes) -> void* {
    void* r = (void*)p;
    p += (bytes + 255) & ~((size_t)255);
    return r;
  };
  float* x    = (float*)alloc((size_t)T * D * 4);          // 6.3 MB
  float* xn   = (float*)alloc((size_t)T * D * 4);          // 6.3 MB (head xb)
  float* qkvb = (float*)alloc((size_t)T * 2304 * 4);       // 18.9 MB
  float* att  = (float*)alloc((size_t)T * D * 4);          // 6.3 MB = pbuf
  float* kvp  = (float*)alloc((size_t)8 * 24 * 4160 * 4);  // 3.2 MB
  float* kv   = (float*)alloc((size_t)24 * 4160 * 4);
  float* srow = (float*)alloc((size_t)T * 4 * 4);
  float* glog = (float*)alloc((size_t)T * 4 * 4);
  float* bqkv = (float*)alloc((size_t)2304 * 4);
  int*   list = (int*)alloc((size_t)NE * 2048 * 4);
  int*   rnkl = (int*)alloc((size_t)NE * 2048 * 4);
  int*   cnt  = (int*)alloc((size_t)16);
  // Shared activation-plane buffer (2 x T x 768 bf16 = 6.29 MB) fits in att.
  unsigned short* pbuf = (unsigned short*)att;
  // d_out (262.1 MB) scratch overlays, all dead before the head writes it:
  //   hseP @0:    2 planes x [4][2048][3072] bf16 = 100.7 MB
  //   xc   @100.7: 8 fp32 buffers x [T][768]      =  50.3 MB
  //   wp   @151.0: weight planes slot             <= 37.7 MB (2 planes)
  bf16* hseP = (bf16*)d_out;
  float* xc = (float*)((char*)d_out + (size_t)2 * PSH * 2);
  unsigned short* wp =
      (unsigned short*)((char*)d_out + (size_t)2 * PSH * 2 +
                        (size_t)8 * T * D * 4);
  unsigned short* wqkvP = wp;                       // 2 planes x [2304][768]
  unsigned short* owP   = wp + (size_t)2 * PSQ;     // 2 planes x [768][768]
  // Head-phase overlays (dead regions): xb on xn; hwT on qkvb.
  bf16* xb  = (bf16*)xn;
  bf16* hwT = (bf16*)qkvb;

  k_embed<<<dim3(6144), 256, 0, stream>>>(tokens, emb, pos, x);

  for (int l = 0; l < NL; ++l) {
    const size_t DD = (size_t)D * D;
    // attention weight planes: qw/kw/vw -> wqkvP rows 0/768/1536; ow -> owP
    k_tsplit2<<<dim3(12, 12, 1), 256, 0, stream>>>(qw + l * DD, 0, wqkvP, 0,
                                                   PSQ, D, D);
    k_tsplit2<<<dim3(12, 12, 1), 256, 0, stream>>>(
        kw + l * DD, 0, wqkvP + (size_t)768 * 768, 0, PSQ, D, D);
    k_tsplit2<<<dim3(12, 12, 1), 256, 0, stream>>>(
        vw + l * DD, 0, wqkvP + (size_t)1536 * 768, 0, PSQ, D, D);
    k_tsplit2<<<dim3(12, 12, 1), 256, 0, stream>>>(ow + l * DD, 0, owP, 0,
                                                   PSO, D, D);
    k_cat3<<<dim3(9), 256, 0, stream>>>(qb + l * D, kb + l * D, vb + l * D,
                                        bqkv);

    // attention (bf16x2 fp32-faithful GEMMs)
    k_ln<<<dim3(T), 256, 0, stream>>>(x, ln1g + l * D, ln1b + l * D, pbuf,
                                      nullptr, nullptr, nullptr);
    k_g3<1><<<dim3(18, 16, 1), 256, 0, stream>>>(
        (const bf16*)pbuf, PSX, (const bf16*)wqkvP, PSQ, bqkv, qkvb, 2304);
    k_kvpart<<<dim3(24, 8), 256, 0, stream>>>(qkvb, kvp);
    k_kvred<<<dim3(390), 256, 0, stream>>>(kvp, kv);
    k_attnout<<<dim3(T), 256, 0, stream>>>(qkvb, kv, pbuf);
    k_g3<2><<<dim3(6, 16, 1), 256, 0, stream>>>(
        (const bf16*)pbuf, PSX, (const bf16*)owP, PSO, ob + l * D, x, D);

    // MoE (sparse top-2, bf16x2 MFMA; flat grids)
    k_ln<<<dim3(T), 256, 0, stream>>>(x, ln2g + l * D, ln2b + l * D, pbuf,
                                      gw + (size_t)l * D * NE, gb + l * NE,
                                      glog);
    k_scan<<<dim3(1), 256, 0, stream>>>(glog, srow, list, rnkl, cnt);
    k_tsplit2<<<dim3(48, 12, 4), 256, 0, stream>>>(
        w1 + (size_t)l * NE * D * DH, (long)D * DH, wp, EB, PSW, DH, D);
    k_moe3<0><<<dim3(24, 16, 4), 256, 0, stream>>>(
        (const bf16*)pbuf, PSX, (const bf16*)wp, PSW, b1 + (size_t)l * NE * DH,
        hseP, nullptr, srow, list, rnkl, cnt);
    k_tsplit2<<<dim3(12, 48, 4), 256, 0, stream>>>(
        w2 + (size_t)l * NE * DH * D, (long)DH * D, wp, EB, PSW, D, DH);
    k_moe3<1><<<dim3(6, 16, 16), 256, 0, stream>>>(
        hseP, PSH, (const bf16*)wp, PSW, nullptr, nullptr, xc, srow, list,
        rnkl, cnt);
    k_moeadd<<<dim3(6144), 256, 0, stream>>>(x, xc, srow,
                                             b2 + (size_t)l * NE * D);
  }

  // ------------------------------------------------------------- head -------
  k_f2b<<<dim3(6144), 256, 0, stream>>>(x, xb);
  for (int half = 0; half < 2; ++half) {
    k_transpose<<<dim3(250, 12, 1), 256, 0, stream>>>(
        hw + half * 16000, (unsigned short*)hwT, V, D);
    k_bgemm<<<dim3(125, 16, 1), 256, 0, stream>>>(
        xb, hwT, hb + half * 16000, (float*)d_out + half * 16000, V, D);
  }
}

// Round 15
// 1927.024 us; speedup vs baseline: 1.4731x; 1.0292x over previous
//
#include <hip/hip_runtime.h>
#include <hip/hip_bf16.h>
#include <cstdint>
#include <cstddef>

typedef __hip_bfloat16 bf16;
typedef __attribute__((ext_vector_type(8))) short bf16x8;
typedef __attribute__((ext_vector_type(4))) float f32x4;

#define DEV __device__ __forceinline__

static constexpr int D  = 768;
static constexpr int NH = 12;
static constexpr int NE = 4;
static constexpr int DH = 3072;
static constexpr int L  = 1024;
static constexpr int T  = 2048;
static constexpr int V  = 32000;
static constexpr int NL = 4;

static constexpr long PSX = (long)T * 768;        // activation plane stride
static constexpr long PSH = (long)NE * 2048 * DH; // hse plane stride
static constexpr long PSW = (long)NE * DH * 768;  // MoE weight plane stride
static constexpr long PSQ = (long)2304 * 768;     // qkv weight plane stride
static constexpr long PSO = (long)768 * 768;      // o-proj weight plane stride
static constexpr long EB  = (long)DH * 768;       // per-expert weight elems

DEV float b2f(bf16 v) { return __bfloat162float(v); }
DEV bf16 f2b(float f) { return __float2bfloat16(f); }
DEV unsigned short f2bu(float f) {
  bf16 b = f2b(f);
  return *reinterpret_cast<unsigned short*>(&b);
}
DEV float gelu(float v) {
  return 0.5f * v * (1.f + erff(v * 0.70710678118654752f));
}
// fp32 -> 2x bf16 planes (a ~= p0+p1 to ~2^-18 rel; 3-term product error
// ~1e-5, 2^9 x smaller than the bf16 noise that flipped routing in r1-r4).
DEV void split2u(float a, unsigned short& x0, unsigned short& x1) {
  bf16 c0 = f2b(a);
  float r1 = a - b2f(c0);
  bf16 c1 = f2b(r1);
  x0 = *reinterpret_cast<unsigned short*>(&c0);
  x1 = *reinterpret_cast<unsigned short*>(&c1);
}

// ---------------------------------------------------------------- staging ----
DEV void gld16(const void* g, short* ldsbase, int lane) {
#if __has_builtin(__builtin_amdgcn_global_load_lds)
  (void)lane;
  __builtin_amdgcn_global_load_lds(
      (const __attribute__((address_space(1))) unsigned int*)g,
      (__attribute__((address_space(3))) unsigned int*)ldsbase, 16, 0, 0);
#else
  *reinterpret_cast<bf16x8*>(ldsbase + lane * 8) =
      *reinterpret_cast<const bf16x8*>(g);
#endif
}

// 3-term bf16x2 MFMA accumulate helper (a0b0 + a0b1 + a1b0).
DEV void mfma3(f32x4 acc[4][4], const bf16x8 af[2][4], const short* ldsB,
               int wn, int ln, int kg) {
#pragma unroll
  for (int c = 0; c < 4; ++c) {
    const int bo = (wn + c * 16 + ln) * 32 + kg * 8;
    const bf16x8 bv0 = *reinterpret_cast<const bf16x8*>(&ldsB[bo]);
    const bf16x8 bv1 = *reinterpret_cast<const bf16x8*>(&ldsB[4096 + bo]);
#pragma unroll
    for (int r = 0; r < 4; ++r) {
      f32x4 a = acc[r][c];
      a = __builtin_amdgcn_mfma_f32_16x16x32_bf16(af[1][r], bv0, a, 0, 0, 0);
      a = __builtin_amdgcn_mfma_f32_16x16x32_bf16(af[0][r], bv1, a, 0, 0, 0);
      a = __builtin_amdgcn_mfma_f32_16x16x32_bf16(af[0][r], bv0, a, 0, 0, 0);
      acc[r][c] = a;
    }
  }
}

// --------------------------------------- dense bf16x2 fp32-faithful GEMM ----
// C[2048,N] = A @ B + bias; A planes [2048][768], B^T planes [N][768], K=768.
// EPI 1: qkv (bias from qb/kb/vb by col; elu+1 for col<1536) -> fp32 out.
// EPI 2: out += acc + bias.
template <int EPI>
__global__ __launch_bounds__(256) void k_g3(
    const bf16* __restrict__ Ap, long psA,
    const bf16* __restrict__ Bp, long psB,
    const float* __restrict__ bias,
    const float* __restrict__ bias2,
    const float* __restrict__ bias3,
    float* __restrict__ outp, int ldc) {
  const int m0 = blockIdx.y * 128;
  const int n0 = blockIdx.x * 128;
  const int tid  = threadIdx.x;
  const int wave = tid >> 6;
  const int lane = tid & 63;
  const int wm = (wave >> 1) * 64;
  const int wn = (wave & 1) * 64;
  const int ln = lane & 15;
  const int kg = lane >> 4;
  const int rowA = lane >> 2;
  const int colK = (lane & 3) * 8;

  __shared__ short lds[16384];  // A planes @0/4096, B planes @8192/12288

  f32x4 acc[4][4] = {};

  for (int kt = 0; kt < 768; kt += 32) {
    __syncthreads();
#pragma unroll
    for (int c2 = 0; c2 < 2; ++c2) {
      const int chunk = c2 * 4 + wave;
      const int r16 = chunk * 16 + rowA;
      const size_t arow = (size_t)(m0 + r16);
      const size_t brow = (size_t)(n0 + r16);
#pragma unroll
      for (int p = 0; p < 2; ++p) {
        gld16(Ap + (size_t)p * psA + arow * 768 + kt + colK,
              &lds[p * 4096 + chunk * 512], lane);
        gld16(Bp + (size_t)p * psB + brow * 768 + kt + colK,
              &lds[8192 + p * 4096 + chunk * 512], lane);
      }
    }
    __syncthreads();

    bf16x8 af[2][4];
#pragma unroll
    for (int r = 0; r < 4; ++r)
#pragma unroll
      for (int p = 0; p < 2; ++p)
        af[p][r] = *reinterpret_cast<const bf16x8*>(
            &lds[p * 4096 + (wm + r * 16 + ln) * 32 + kg * 8]);
    mfma3(acc, af, &lds[8192], wn, ln, kg);
  }

#pragma unroll
  for (int c = 0; c < 4; ++c) {
    const int col = n0 + wn + c * 16 + ln;
    float bvl;
    if constexpr (EPI == 1) {
      bvl = (col < 768) ? bias[col]
                        : (col < 1536 ? bias2[col - 768] : bias3[col - 1536]);
    } else {
      bvl = bias[col];
    }
#pragma unroll
    for (int r = 0; r < 4; ++r)
#pragma unroll
      for (int j = 0; j < 4; ++j) {
        const int row = m0 + wm + r * 16 + kg * 4 + j;
        const float v = acc[r][c][j] + bvl;
        const size_t idx = (size_t)row * ldc + col;
        if constexpr (EPI == 1) {
          outp[idx] = (col < 1536) ? (v > 0.f ? v + 1.f : expf(v)) : v;
        } else {
          outp[idx] += v;
        }
      }
  }
}

// ----------------------------------------- bf16x2 split-precision MoE GEMM --
// PH=0 (UP):  grid (24,16,4), flat mapping. Gather rows via list[z];
//             out = hse planes (gelu*srow, split2).
// PH=1 (DOWN):grid (6,16,16); blockIdx.z = z*4+kc (split-K 3072 = 4x768);
//             out xc[(kc*2+rank)][tok][768] fp32.
template <int PH>
__global__ __launch_bounds__(256) void k_moe3(
    const bf16* __restrict__ Ap, long psA,
    const bf16* __restrict__ Bp, long psB,
    const float* __restrict__ b1z,
    bf16* __restrict__ hseP,
    float* __restrict__ xc,
    const float* __restrict__ srow, const int* __restrict__ list,
    const int* __restrict__ rnkl, const int* __restrict__ cnt) {
  const int zz = blockIdx.z;
  const int z  = (PH == 0) ? zz : (zz >> 2);
  const int kc = (PH == 0) ? 0 : (zz & 3);
  const int m0 = blockIdx.y * 128;
  const int cz = cnt[z];
  if (m0 >= cz) return;
  const int n0 = blockIdx.x * 128;
  constexpr int LD = PH ? 3072 : 768;
  const int kBeg = kc * 768;

  const int tid  = threadIdx.x;
  const int wave = tid >> 6;
  const int lane = tid & 63;
  const int wm = (wave >> 1) * 64;
  const int wn = (wave & 1) * 64;
  const int ln = lane & 15;
  const int kg = lane >> 4;
  const int rowA = lane >> 2;
  const int colK = (lane & 3) * 8;

  __shared__ short lds[16384];
  __shared__ int rows[128];
  __shared__ int rnks[128];
  if (tid < 128) {
    rows[tid] = list[z * 2048 + m0 + tid];
    if (PH == 1) rnks[tid] = rnkl[z * 2048 + m0 + tid];
  }

  f32x4 acc[4][4] = {};
  const bf16* Bz = Bp + (size_t)z * EB;

  for (int kt = kBeg; kt < kBeg + 768; kt += 32) {
    __syncthreads();
#pragma unroll
    for (int c2 = 0; c2 < 2; ++c2) {
      const int chunk = c2 * 4 + wave;
      const int r16 = chunk * 16 + rowA;
      const size_t arow =
          (PH == 0) ? (size_t)rows[r16] : (size_t)(z * 2048 + m0 + r16);
      const size_t brow = (size_t)(n0 + r16);
#pragma unroll
      for (int p = 0; p < 2; ++p) {
        gld16(Ap + (size_t)p * psA + arow * LD + kt + colK,
              &lds[p * 4096 + chunk * 512], lane);
        gld16(Bz + (size_t)p * psB + brow * LD + kt + colK,
              &lds[8192 + p * 4096 + chunk * 512], lane);
      }
    }
    __syncthreads();

    bf16x8 af[2][4];
#pragma unroll
    for (int r = 0; r < 4; ++r)
#pragma unroll
      for (int p = 0; p < 2; ++p)
        af[p][r] = *reinterpret_cast<const bf16x8*>(
            &lds[p * 4096 + (wm + r * 16 + ln) * 32 + kg * 8]);
    mfma3(acc, af, &lds[8192], wn, ln, kg);
  }

#pragma unroll
  for (int c = 0; c < 4; ++c) {
    const int col = n0 + wn + c * 16 + ln;
    float bvl = 0.f;
    if constexpr (PH == 0) bvl = b1z[z * 3072 + col];
#pragma unroll
    for (int r = 0; r < 4; ++r)
#pragma unroll
      for (int j = 0; j < 4; ++j) {
        const int rl = wm + r * 16 + kg * 4 + j;
        if constexpr (PH == 0) {
          const int pos = m0 + rl;
          const int tok = rows[rl];
          const float s = srow[tok * 4 + z];
          const float h = s * gelu(acc[r][c][j] + bvl);
          unsigned short u0, u1;
          split2u(h, u0, u1);
          unsigned short* hp = (unsigned short*)hseP;
          const size_t o = ((size_t)z * 2048 + pos) * 3072 + col;
          hp[o] = u0;
          hp[PSH + o] = u1;
        } else {
          if (m0 + rl < cz) {
            const int tok = rows[rl];
            const int rk = rnks[rl];
            xc[((size_t)(kc * 2 + rk) * T + tok) * 768 + col] = acc[r][c][j];
          }
        }
      }
  }
}

// ----------------------------------------------------- bf16 MFMA head GEMM --
__global__ __launch_bounds__(256) void k_bgemm(
    const bf16* __restrict__ A, const bf16* __restrict__ BT,
    const float* __restrict__ bias, float* __restrict__ outp,
    int ldc, int Keff) {
  const int tid  = threadIdx.x;
  const int wave = tid >> 6;
  const int lane = tid & 63;
  const int m0 = blockIdx.y * 128;
  const int n0 = blockIdx.x * 128;
  const int wm = (wave >> 1) * 64;
  const int wn = (wave & 1) * 64;
  const int ln = lane & 15;
  const int kg = lane >> 4;

  __shared__ short lds[8192];

  f32x4 acc[4][4] = {};

  const int rowA = lane >> 2;
  const int colK = (lane & 3) * 8;

  for (int kt = 0; kt < Keff; kt += 32) {
    __syncthreads();
#pragma unroll
    for (int c2 = 0; c2 < 2; ++c2) {
      const int chunk = c2 * 4 + wave;
      const int row = chunk * 16 + rowA;
      gld16(A + (size_t)(m0 + row) * 768 + kt + colK, &lds[chunk * 512], lane);
      gld16(BT + (size_t)(n0 + row) * 768 + kt + colK, &lds[4096 + chunk * 512],
            lane);
    }
    __syncthreads();

    bf16x8 af[4], bv[4];
#pragma unroll
    for (int r = 0; r < 4; ++r)
      af[r] = *reinterpret_cast<const bf16x8*>(
          &lds[(wm + r * 16 + ln) * 32 + kg * 8]);
#pragma unroll
    for (int c = 0; c < 4; ++c)
      bv[c] = *reinterpret_cast<const bf16x8*>(
          &lds[4096 + (wn + c * 16 + ln) * 32 + kg * 8]);

#pragma unroll
    for (int r = 0; r < 4; ++r)
#pragma unroll
      for (int c = 0; c < 4; ++c)
        acc[r][c] = __builtin_amdgcn_mfma_f32_16x16x32_bf16(
            af[r], bv[c], acc[r][c], 0, 0, 0);
  }

#pragma unroll
  for (int c = 0; c < 4; ++c) {
    const int nn = n0 + wn + c * 16 + ln;
    const float bvl = bias[nn];
#pragma unroll
    for (int r = 0; r < 4; ++r)
#pragma unroll
      for (int j = 0; j < 4; ++j) {
        const int mm = m0 + wm + r * 16 + kg * 4 + j;
        outp[(size_t)mm * ldc + nn] = acc[r][c][j] + bvl;
      }
  }
}

// -------------------------------------------------------------- transposes ---
// fp32 [R][C] -> bf16 [C][R] (head weights)
__global__ __launch_bounds__(256) void k_transpose(
    const float* __restrict__ in, unsigned short* __restrict__ out,
    int C, int outStride) {
  __shared__ float t[64][65];
  const int tx = threadIdx.x & 15, ty = threadIdx.x >> 4;
  const int r0 = blockIdx.y * 64, c0 = blockIdx.x * 64;
#pragma unroll
  for (int i = 0; i < 4; ++i) {
    const int r = ty + i * 16;
    const float4 v = *(const float4*)&in[(size_t)(r0 + r) * C + c0 + tx * 4];
    t[r][tx * 4 + 0] = v.x;
    t[r][tx * 4 + 1] = v.y;
    t[r][tx * 4 + 2] = v.z;
    t[r][tx * 4 + 3] = v.w;
  }
  __syncthreads();
#pragma unroll
  for (int i = 0; i < 4; ++i) {
    const int a = ty + i * 16;
    ushort4 v;
    v.x = f2bu(t[tx * 4 + 0][a]);
    v.y = f2bu(t[tx * 4 + 1][a]);
    v.z = f2bu(t[tx * 4 + 2][a]);
    v.w = f2bu(t[tx * 4 + 3][a]);
    *(ushort4*)&out[(size_t)(c0 + a) * outStride + r0 + tx * 4] = v;
  }
}

// fp32 [R][C] -> 2x bf16 planes [C][R], z batches (experts).
__global__ __launch_bounds__(256) void k_tsplit2(
    const float* __restrict__ in, long inE,
    unsigned short* __restrict__ out, long outE, long planeS,
    int C, int outStride) {
  in += (size_t)blockIdx.z * inE;
  unsigned short* o = out + (size_t)blockIdx.z * outE;
  __shared__ float t[64][65];
  const int tx = threadIdx.x & 15, ty = threadIdx.x >> 4;
  const int r0 = blockIdx.y * 64, c0 = blockIdx.x * 64;
#pragma unroll
  for (int i = 0; i < 4; ++i) {
    const int r = ty + i * 16;
    const float4 v = *(const float4*)&in[(size_t)(r0 + r) * C + c0 + tx * 4];
    t[r][tx * 4 + 0] = v.x;
    t[r][tx * 4 + 1] = v.y;
    t[r][tx * 4 + 2] = v.z;
    t[r][tx * 4 + 3] = v.w;
  }
  __syncthreads();
#pragma unroll
  for (int i = 0; i < 4; ++i) {
    const int a = ty + i * 16;
    ushort4 u0, u1;
    split2u(t[tx * 4 + 0][a], u0.x, u1.x);
    split2u(t[tx * 4 + 1][a], u0.y, u1.y);
    split2u(t[tx * 4 + 2][a], u0.z, u1.z);
    split2u(t[tx * 4 + 3][a], u0.w, u1.w);
    const size_t off = (size_t)(c0 + a) * outStride + r0 + tx * 4;
    *(ushort4*)&o[off] = u0;
    *(ushort4*)&o[planeS + off] = u1;
  }
}

// Batched attention-weight split: z=0..3 -> {qw,kw,vw,ow} (all 768x768).
struct TSrc {
  const float* s0;
  const float* s1;
  const float* s2;
  const float* s3;
};
__global__ __launch_bounds__(256) void k_tsplitA(
    TSrc ts, unsigned short* __restrict__ wqkvP,
    unsigned short* __restrict__ owP) {
  const int z = blockIdx.z;
  const float* in = (z == 0) ? ts.s0 : (z == 1) ? ts.s1 : (z == 2) ? ts.s2
                                                                   : ts.s3;
  unsigned short* o = (z < 3) ? (wqkvP + (size_t)z * 768 * 768) : owP;
  const long planeS = (z < 3) ? PSQ : PSO;
  __shared__ float t[64][65];
  const int tx = threadIdx.x & 15, ty = threadIdx.x >> 4;
  const int r0 = blockIdx.y * 64, c0 = blockIdx.x * 64;
#pragma unroll
  for (int i = 0; i < 4; ++i) {
    const int r = ty + i * 16;
    const float4 v = *(const float4*)&in[(size_t)(r0 + r) * 768 + c0 + tx * 4];
    t[r][tx * 4 + 0] = v.x;
    t[r][tx * 4 + 1] = v.y;
    t[r][tx * 4 + 2] = v.z;
    t[r][tx * 4 + 3] = v.w;
  }
  __syncthreads();
#pragma unroll
  for (int i = 0; i < 4; ++i) {
    const int a = ty + i * 16;
    ushort4 u0, u1;
    split2u(t[tx * 4 + 0][a], u0.x, u1.x);
    split2u(t[tx * 4 + 1][a], u0.y, u1.y);
    split2u(t[tx * 4 + 2][a], u0.z, u1.z);
    split2u(t[tx * 4 + 3][a], u0.w, u1.w);
    const size_t off = (size_t)(c0 + a) * 768 + r0 + tx * 4;
    *(ushort4*)&o[off] = u0;
    *(ushort4*)&o[planeS + off] = u1;
  }
}

// ------------------------------------------------------------ small kernels --
__global__ void k_embed(const int* __restrict__ tok,
                        const float* __restrict__ emb,
                        const float* __restrict__ pos, float* __restrict__ x) {
  const int idx = blockIdx.x * 256 + threadIdx.x;
  const int t = idx / D, d = idx - t * D;
  const int tk = tok[t];
  x[idx] = emb[(size_t)tk * D + d] + pos[(size_t)(t & (L - 1)) * D + d];
}

// Final: xb = bf16(x + sum xc + moe bias terms)  (fused last-layer moeadd)
__global__ void k_f2bF(const float* __restrict__ x,
                       const float* __restrict__ xc,
                       const float* __restrict__ srow,
                       const float* __restrict__ b2l, bf16* __restrict__ o) {
  const int idx = blockIdx.x * 256 + threadIdx.x;
  const int t = idx / D, n = idx - t * D;
  const float* s = srow + t * 4;
  float acc = x[idx];
#pragma unroll
  for (int c = 0; c < 8; ++c) acc += xc[(size_t)c * T * D + idx];
  acc += s[0] * b2l[n] + s[1] * b2l[D + n] + s[2] * b2l[2 * D + n] +
         s[3] * b2l[3 * D + n];
  o[idx] = f2b(acc);
}

// LayerNorm fp32 in -> 2x bf16 planes out; optional fp32 gate logits (+gb);
// optional fused pre-accumulate (prev layer's moeadd): when xcIn != nullptr,
// x[row] += sum xc + bias terms (exact moeadd order) before LN, written back.
__global__ __launch_bounds__(256) void k_ln(float* __restrict__ x,
                                            const float* __restrict__ g,
                                            const float* __restrict__ bb,
                                            unsigned short* __restrict__ xnp,
                                            const float* __restrict__ gw,
                                            const float* __restrict__ gb,
                                            float* __restrict__ glog,
                                            const float* __restrict__ xcIn,
                                            const float* __restrict__ srowIn,
                                            const float* __restrict__ b2l) {
  const int row = blockIdx.x, tid = threadIdx.x;
  float* xr = x + (size_t)row * D;
  float v0 = xr[tid], v1 = xr[tid + 256], v2 = xr[tid + 512];
  if (xcIn != nullptr) {
    const float* s = srowIn + row * 4;
    auto fuse = [&](float v, int n) {
      const size_t idx = (size_t)row * D + n;
      float a = v;
#pragma unroll
      for (int c = 0; c < 8; ++c) a += xcIn[(size_t)c * T * D + idx];
      a += s[0] * b2l[n] + s[1] * b2l[D + n] + s[2] * b2l[2 * D + n] +
           s[3] * b2l[3 * D + n];
      return a;
    };
    v0 = fuse(v0, tid);
    v1 = fuse(v1, tid + 256);
    v2 = fuse(v2, tid + 512);
    xr[tid] = v0;
    xr[tid + 256] = v1;
    xr[tid + 512] = v2;
  }
  float s = v0 + v1 + v2, s2 = v0 * v0 + v1 * v1 + v2 * v2;
  for (int off = 1; off < 64; off <<= 1) {
    s += __shfl_xor(s, off);
    s2 += __shfl_xor(s2, off);
  }
  __shared__ float rs[4], rs2[4];
  const int w = tid >> 6;
  if ((tid & 63) == 0) { rs[w] = s; rs2[w] = s2; }
  __syncthreads();
  const float S = rs[0] + rs[1] + rs[2] + rs[3];
  const float S2 = rs2[0] + rs2[1] + rs2[2] + rs2[3];
  const float mean = S * (1.f / 768.f);
  const float var = fmaxf(S2 * (1.f / 768.f) - mean * mean, 0.f);
  const float rstd = rsqrtf(var + 1e-5f);
  const float o0 = (v0 - mean) * rstd * g[tid]       + bb[tid];
  const float o1 = (v1 - mean) * rstd * g[tid + 256] + bb[tid + 256];
  const float o2 = (v2 - mean) * rstd * g[tid + 512] + bb[tid + 512];
  {
    const size_t base = (size_t)row * D;
    unsigned short a0, a1;
    split2u(o0, a0, a1);
    xnp[base + tid] = a0;
    xnp[PSX + base + tid] = a1;
    split2u(o1, a0, a1);
    xnp[base + tid + 256] = a0;
    xnp[PSX + base + tid + 256] = a1;
    split2u(o2, a0, a1);
    xnp[base + tid + 512] = a0;
    xnp[PSX + base + tid + 512] = a1;
  }

  if (gw != nullptr) {
    const float4 ga = *(const float4*)&gw[tid * 4];
    const float4 gbv = *(const float4*)&gw[(tid + 256) * 4];
    const float4 gc = *(const float4*)&gw[(tid + 512) * 4];
    float p0 = o0 * ga.x + o1 * gbv.x + o2 * gc.x;
    float p1 = o0 * ga.y + o1 * gbv.y + o2 * gc.y;
    float p2 = o0 * ga.z + o1 * gbv.z + o2 * gc.z;
    float p3 = o0 * ga.w + o1 * gbv.w + o2 * gc.w;
    for (int off = 1; off < 64; off <<= 1) {
      p0 += __shfl_xor(p0, off);
      p1 += __shfl_xor(p1, off);
      p2 += __shfl_xor(p2, off);
      p3 += __shfl_xor(p3, off);
    }
    __shared__ float rg[4][4];
    if ((tid & 63) == 0) {
      rg[w][0] = p0; rg[w][1] = p1; rg[w][2] = p2; rg[w][3] = p3;
    }
    __syncthreads();
    if (tid == 0) {
      float* gl = glog + (size_t)row * 4;
#pragma unroll
      for (int e = 0; e < 4; ++e)
        gl[e] = rg[0][e] + rg[1][e] + rg[2][e] + rg[3][e] + gb[e];
    }
  }
}

// top-2 softmax weights + deterministic per-expert token lists.
__global__ __launch_bounds__(256) void k_scan(const float* __restrict__ glog,
                                              float* __restrict__ srow,
                                              int* __restrict__ list,
                                              int* __restrict__ rnkl,
                                              int* __restrict__ cnt) {
  const int tid = threadIdx.x;
  __shared__ unsigned char e1s[2048], e2s[2048];
  for (int t = tid; t < T; t += 256) {
    float gv[4];
#pragma unroll
    for (int i = 0; i < 4; ++i) gv[i] = glog[t * 4 + i];
    int i1 = 0;
#pragma unroll
    for (int i = 1; i < 4; ++i)
      if (gv[i] > gv[i1]) i1 = i;
    int i2 = -1;
#pragma unroll
    for (int i = 0; i < 4; ++i) {
      if (i == i1) continue;
      if (i2 < 0 || gv[i] > gv[i2]) i2 = i;
    }
    const float e = expf(gv[i2] - gv[i1]);
    const float wa = 1.f / (1.f + e), wb = e / (1.f + e);
    float o[4] = {0.f, 0.f, 0.f, 0.f};
    o[i1] = wa;
    o[i2] = wb;
#pragma unroll
    for (int i = 0; i < 4; ++i) srow[t * 4 + i] = o[i];
    e1s[t] = (unsigned char)i1;
    e2s[t] = (unsigned char)i2;
  }
  __syncthreads();
  const int w = tid >> 6, lane = tid & 63;
  int base = 0;
  for (int c = 0; c < 32; ++c) {
    const int t = c * 64 + lane;
    const bool f1 = (e1s[t] == w);
    const bool f2 = (e2s[t] == w);
    const bool f = f1 || f2;
    const unsigned long long mask = __ballot(f);
    const int mypos = __popcll(mask & ((1ull << lane) - 1ull));
    if (f) {
      list[w * 2048 + base + mypos] = t;
      rnkl[w * 2048 + base + mypos] = f1 ? 0 : 1;
    }
    base += __popcll(mask);
  }
  if (lane == 0) cnt[w] = base;
  for (int ppos = base + lane; ppos < 2048; ppos += 64) {
    list[w * 2048 + ppos] = 0;
    rnkl[w * 2048 + ppos] = 0;
  }
}

// Partial KV/Z over an L-chunk of 128 rows. part[c][bh][e*64+f], Z at +4096.
__global__ __launch_bounds__(256) void k_kvpart(const float* __restrict__ qkv,
                                                float* __restrict__ part) {
  const int bh = blockIdx.x;
  const int b = bh / NH, h = bh % NH;
  const int c = blockIdx.y;
  const int tid = threadIdx.x;
  __shared__ float kf[64], vv[64];
  float acc[16];
#pragma unroll
  for (int j = 0; j < 16; ++j) acc[j] = 0.f;
  float zacc = 0.f;
  const int e = tid >> 2;
  const int f0 = (tid & 3) * 16;
  const int t0 = b * L + c * 128;
  for (int i = 0; i < 128; ++i) {
    __syncthreads();
    const size_t rowb = (size_t)(t0 + i) * 2304;
    if (tid < 64) kf[tid] = qkv[rowb + 768 + h * 64 + tid];
    else if (tid < 128) vv[tid - 64] = qkv[rowb + 1536 + h * 64 + (tid - 64)];
    __syncthreads();
    const float ke = kf[e];
#pragma unroll
    for (int j = 0; j < 16; ++j) acc[j] += ke * vv[f0 + j];
    if (tid < 64) zacc += kf[tid];
  }
  const size_t base = ((size_t)c * 24 + bh) * 4160;
#pragma unroll
  for (int j = 0; j < 16; ++j) part[base + e * 64 + f0 + j] = acc[j];
  if (tid < 64) part[base + 4096 + tid] = zacc;
}

__global__ void k_kvred(const float* __restrict__ part, float* __restrict__ kv) {
  const int idx = blockIdx.x * 256 + threadIdx.x;
  float s = 0.f;
#pragma unroll
  for (int cc = 0; cc < 8; ++cc) s += part[(size_t)cc * 99840 + idx];
  kv[idx] = s;
}

// attention apply; emits 2-plane bf16x2 output for the o-proj g3 GEMM.
__global__ __launch_bounds__(256) void k_attnout(
    const float* __restrict__ qkv, const float* __restrict__ kv,
    unsigned short* __restrict__ attP) {
  const int t = blockIdx.x;
  const int b = t >> 10;
  const int tid = threadIdx.x;
  __shared__ float q[768];
  __shared__ float den[12];
  for (int i = tid; i < 768; i += 256) q[i] = qkv[(size_t)t * 2304 + i];
  __syncthreads();
  if (tid < 12) {
    const float* zz = kv + ((size_t)(b * NH + tid)) * 4160 + 4096;
    float s = 0.f;
#pragma unroll
    for (int e = 0; e < 64; ++e) s += q[tid * 64 + e] * zz[e];
    den[tid] = s + 1e-6f;
  }
  __syncthreads();
  for (int i = tid; i < 768; i += 256) {
    const int h = i >> 6, f = i & 63;
    const float* Kv = kv + ((size_t)(b * NH + h)) * 4160;
    float s = 0.f;
#pragma unroll
    for (int e = 0; e < 64; ++e) s += q[h * 64 + e] * Kv[e * 64 + f];
    const float r = s / den[h];
    unsigned short u0, u1;
    split2u(r, u0, u1);
    const size_t o = (size_t)t * 768 + i;
    attP[o] = u0;
    attP[PSX + o] = u1;
  }
}

// ------------------------------------------------------------------ launch ---
extern "C" void kernel_launch(void* const* d_in, const int* in_sizes, int n_in,
                              void* d_out, int out_size, void* d_ws,
                              size_t ws_size, hipStream_t stream) {
  const int*   tokens = (const int*)d_in[0];
  const float* emb  = (const float*)d_in[1];
  const float* pos  = (const float*)d_in[2];
  const float* qw   = (const float*)d_in[3];
  const float* qb   = (const float*)d_in[4];
  const float* kw   = (const float*)d_in[5];
  const float* kb   = (const float*)d_in[6];
  const float* vw   = (const float*)d_in[7];
  const float* vb   = (const float*)d_in[8];
  const float* ow   = (const float*)d_in[9];
  const float* ob   = (const float*)d_in[10];
  const float* ln1g = (const float*)d_in[11];
  const float* ln1b = (const float*)d_in[12];
  const float* ln2g = (const float*)d_in[13];
  const float* ln2b = (const float*)d_in[14];
  const float* gw   = (const float*)d_in[15];
  const float* gb   = (const float*)d_in[16];
  const float* w1   = (const float*)d_in[17];
  const float* b1   = (const float*)d_in[18];
  const float* w2   = (const float*)d_in[19];
  const float* b2   = (const float*)d_in[20];
  const float* hw   = (const float*)d_in[21];
  const float* hb   = (const float*)d_in[22];

  char* p = (char*)d_ws;
  auto alloc = [&](size_t bytes) -> void* {
    void* r = (void*)p;
    p += (bytes + 255) & ~((size_t)255);
    return r;
  };
  float* x    = (float*)alloc((size_t)T * D * 4);          // 6.3 MB
  float* xn   = (float*)alloc((size_t)T * D * 4);          // 6.3 MB (head xb)
  float* qkvb = (float*)alloc((size_t)T * 2304 * 4);       // 18.9 MB
  float* att  = (float*)alloc((size_t)T * D * 4);          // 6.3 MB = pbuf
  float* kvp  = (float*)alloc((size_t)8 * 24 * 4160 * 4);  // 3.2 MB
  float* kv   = (float*)alloc((size_t)24 * 4160 * 4);
  float* srow = (float*)alloc((size_t)T * 4 * 4);
  float* glog = (float*)alloc((size_t)T * 4 * 4);
  int*   list = (int*)alloc((size_t)NE * 2048 * 4);
  int*   rnkl = (int*)alloc((size_t)NE * 2048 * 4);
  int*   cnt  = (int*)alloc((size_t)16);
  // Shared activation-plane buffer (2 x T x 768 bf16 = 6.29 MB) fits in att.
  unsigned short* pbuf = (unsigned short*)att;
  // d_out (262.1 MB) scratch overlays, all dead before the head writes it:
  //   hseP @0:    2 planes x [4][2048][3072] bf16 = 100.7 MB
  //   xc   @100.7: 8 fp32 buffers x [T][768]      =  50.3 MB
  //   wp   @151.0: weight planes slot             <= 37.7 MB (2 planes)
  bf16* hseP = (bf16*)d_out;
  float* xc = (float*)((char*)d_out + (size_t)2 * PSH * 2);
  unsigned short* wp =
      (unsigned short*)((char*)d_out + (size_t)2 * PSH * 2 +
                        (size_t)8 * T * D * 4);
  unsigned short* wqkvP = wp;                       // 2 planes x [2304][768]
  unsigned short* owP   = wp + (size_t)2 * PSQ;     // 2 planes x [768][768]
  // Head-phase overlays (dead regions): xb on xn; hwT on qkvb.
  bf16* xb  = (bf16*)xn;
  bf16* hwT = (bf16*)qkvb;

  k_embed<<<dim3(6144), 256, 0, stream>>>(tokens, emb, pos, x);

  for (int l = 0; l < NL; ++l) {
    const size_t DD = (size_t)D * D;
    // batched attention weight planes: qw/kw/vw -> wqkvP rows; ow -> owP
    TSrc ts{qw + l * DD, kw + l * DD, vw + l * DD, ow + l * DD};
    k_tsplitA<<<dim3(12, 12, 4), 256, 0, stream>>>(ts, wqkvP, owP);

    // attention (bf16x2 fp32-faithful GEMMs); LN1 fuses prev layer's moeadd
    k_ln<<<dim3(T), 256, 0, stream>>>(
        x, ln1g + l * D, ln1b + l * D, pbuf, nullptr, nullptr, nullptr,
        (l > 0) ? xc : nullptr, srow, b2 + (size_t)(l - 1) * NE * D);
    k_g3<1><<<dim3(18, 16, 1), 256, 0, stream>>>(
        (const bf16*)pbuf, PSX, (const bf16*)wqkvP, PSQ, qb + l * D,
        kb + l * D, vb + l * D, qkvb, 2304);
    k_kvpart<<<dim3(24, 8), 256, 0, stream>>>(qkvb, kvp);
    k_kvred<<<dim3(390), 256, 0, stream>>>(kvp, kv);
    k_attnout<<<dim3(T), 256, 0, stream>>>(qkvb, kv, pbuf);
    k_g3<2><<<dim3(6, 16, 1), 256, 0, stream>>>(
        (const bf16*)pbuf, PSX, (const bf16*)owP, PSO, ob + l * D, nullptr,
        nullptr, x, D);

    // MoE (sparse top-2, bf16x2 MFMA)
    k_ln<<<dim3(T), 256, 0, stream>>>(
        x, ln2g + l * D, ln2b + l * D, pbuf, gw + (size_t)l * D * NE,
        gb + l * NE, glog, nullptr, nullptr, nullptr);
    k_scan<<<dim3(1), 256, 0, stream>>>(glog, srow, list, rnkl, cnt);
    k_tsplit2<<<dim3(48, 12, 4), 256, 0, stream>>>(
        w1 + (size_t)l * NE * D * DH, (long)D * DH, wp, EB, PSW, DH, D);
    k_moe3<0><<<dim3(24, 16, 4), 256, 0, stream>>>(
        (const bf16*)pbuf, PSX, (const bf16*)wp, PSW, b1 + (size_t)l * NE * DH,
        hseP, nullptr, srow, list, rnkl, cnt);
    k_tsplit2<<<dim3(12, 48, 4), 256, 0, stream>>>(
        w2 + (size_t)l * NE * DH * D, (long)DH * D, wp, EB, PSW, D, DH);
    k_moe3<1><<<dim3(6, 16, 16), 256, 0, stream>>>(
        hseP, PSH, (const bf16*)wp, PSW, nullptr, nullptr, xc, srow, list,
        rnkl, cnt);
    // moeadd fused into next LN1 (layers 0..2) or final k_f2bF (layer 3)
  }

  // ------------------------------------------------------------- head -------
  k_f2bF<<<dim3(6144), 256, 0, stream>>>(x, xc, srow,
                                         b2 + (size_t)3 * NE * D, xb);
  for (int half = 0; half < 2; ++half) {
    k_transpose<<<dim3(250, 12, 1), 256, 0, stream>>>(
        hw + half * 16000, (unsigned short*)hwT, V, D);
    k_bgemm<<<dim3(125, 16, 1), 256, 0, stream>>>(
        xb, hwT, hb + half * 16000, (float*)d_out + half * 16000, V, D);
  }
}